// Round 1
// 260.450 us; speedup vs baseline: 1.0952x; 1.0952x over previous
//
#include <hip/hip_runtime.h>
#include <hip/hip_bf16.h>

// GraphSAGE 2-layer, N=100K, E=1.6M, 128->128(relu)->64, log_softmax. fp32 in/out.
//
//   p = fp8(x@Wl1); q = bf16(x@Wr1 + b1)      (MFMA proj, operand-swapped, LDS-staged W)
//   h = bf16(relu(mean_nbr(p) + q))            (r5 gather: 16 lanes/edge, 8B)
//   u = fp8(h@Wl2); v = bf16(h@Wr2 + b2)       (MFMA proj, LDS-staged W)
//   out = log_softmax(mean_nbr(u) + v)         (r5 gather: 8 lanes/edge, 8B)
//
// r9: k2 was latency-bound (MfmaUtil 3.6%, VALUBusy 6.9%, occ 16.7%).
//  - proj waves re-streamed 64KB weights from L2 per 16 rows (L1 thrash, 400MB L2
//    traffic). Now: weights staged once per block into LDS (linear copy ->
//    conflict-free ds_read_b128, 32-bit LDS addressing).
//  - k2/proj2 moved to 512-thread blocks (8 waves x 16 rows, 2 blocks/CU via 64KB
//    dyn LDS = 16 waves/CU resident).
//  - CSR: uint4-vectorized histogram+scatter (32 -> 4-wide iters), wave-shuffle scan
//    (18 barriers -> 2).

typedef __attribute__((ext_vector_type(8))) short short8;   // 8 x bf16 = 4 VGPRs
typedef __attribute__((ext_vector_type(4))) float f32x4;
typedef __attribute__((ext_vector_type(2))) float f32x2;

#define NPB 512          // nodes per bucket (dst >> 9)
#define BCAP 16384       // edge capacity per bucket (mean 8163)
#define CHUNK 8192       // edges per bucket_scatter block

__device__ __forceinline__ ushort f2bf(float f) {           // round-to-nearest-even
    unsigned u = __float_as_uint(f);
    return (ushort)((u + 0x7fff + ((u >> 16) & 1)) >> 16);
}
__device__ __forceinline__ float bflo(unsigned v) { return __uint_as_float(v << 16); }
__device__ __forceinline__ float bfhi(unsigned v) { return __uint_as_float(v & 0xffff0000u); }
__device__ __forceinline__ unsigned pk4bf(float a, float b) {
    return (unsigned)f2bf(a) | ((unsigned)f2bf(b) << 16);
}
__device__ __forceinline__ f32x2 shflx2(f32x2 v, int m) {
    f32x2 r; r[0] = __shfl_xor(v[0], m); r[1] = __shfl_xor(v[1], m); return r;
}

// ---------- weight repack into MFMA fragment order ---------------------------------
// Wf idx = ((ct*16 + kc)*16 + m)*8 + j holds W[k=kc*8+j][c=ct*16+m]
__device__ __forceinline__ void wfrag_one(const float* W, ushort* Wf, int i, int COLS) {
    int j = i & 7, m = (i >> 3) & 15, kc = (i >> 7) & 15, ct = i >> 11;
    Wf[i] = f2bf(W[(kc * 8 + j) * COLS + ct * 16 + m]);
}

// ---------- K1: bucket_scatter (blocks 0..NSC) || cvt_w (rest) ---------------------
__global__ void __launch_bounds__(256)
k1_scatter_cvtw(const int* __restrict__ src, const int* __restrict__ dst,
                int* __restrict__ bcount, unsigned* __restrict__ bbuf, int E, int NSC,
                const float* __restrict__ Wl1, const float* __restrict__ Wr1,
                const float* __restrict__ Wl2, const float* __restrict__ Wr2,
                ushort* __restrict__ Wf_l1, ushort* __restrict__ Wf_r1,
                ushort* __restrict__ Wf_l2, ushort* __restrict__ Wf_r2) {
    int tid = threadIdx.x;
    if ((int)blockIdx.x >= NSC) {
        int i = ((int)blockIdx.x - NSC) * 256 + tid;   // 49152 total
        if (i < 16384)       wfrag_one(Wl1, Wf_l1, i, 128);
        else if (i < 32768)  wfrag_one(Wr1, Wf_r1, i - 16384, 128);
        else if (i < 40960)  wfrag_one(Wl2, Wf_l2, i - 32768, 64);
        else if (i < 49152)  wfrag_one(Wr2, Wf_r2, i - 40960, 64);
        return;
    }
    __shared__ unsigned entry[CHUNK];        // 32 KB: (src<<9)|(dst&511)
    __shared__ unsigned char ebkt[CHUNK];    // 8 KB: bucket id (dst>>9 < 256)
    __shared__ int lhist[256], lbase[256], lcur[256];
    lhist[tid] = 0;
    __syncthreads();
    int e0 = blockIdx.x * CHUNK;
    int cnt = min(CHUNK, E - e0);
    int nv = cnt >> 2;
    for (int t = tid; t < nv; t += 256) {
        int4 d4 = ((const int4*)(dst + e0))[t];
        int4 s4 = ((const int4*)(src + e0))[t];
        int i = t * 4;
        int b0 = d4.x >> 9, b1 = d4.y >> 9, b2 = d4.z >> 9, b3 = d4.w >> 9;
        entry[i + 0] = ((unsigned)s4.x << 9) | (unsigned)(d4.x & 511);
        entry[i + 1] = ((unsigned)s4.y << 9) | (unsigned)(d4.y & 511);
        entry[i + 2] = ((unsigned)s4.z << 9) | (unsigned)(d4.z & 511);
        entry[i + 3] = ((unsigned)s4.w << 9) | (unsigned)(d4.w & 511);
        ebkt[i + 0] = (unsigned char)b0; ebkt[i + 1] = (unsigned char)b1;
        ebkt[i + 2] = (unsigned char)b2; ebkt[i + 3] = (unsigned char)b3;
        atomicAdd(&lhist[b0], 1); atomicAdd(&lhist[b1], 1);
        atomicAdd(&lhist[b2], 1); atomicAdd(&lhist[b3], 1);
    }
    for (int i = (nv << 2) + tid; i < cnt; i += 256) {
        int d = dst[e0 + i], s = src[e0 + i];
        int b = d >> 9;
        entry[i] = ((unsigned)s << 9) | (unsigned)(d & 511);
        ebkt[i] = (unsigned char)b;
        atomicAdd(&lhist[b], 1);
    }
    __syncthreads();
    int h = lhist[tid];
    lbase[tid] = (h > 0) ? atomicAdd(&bcount[tid], h) : 0;
    lcur[tid] = 0;
    __syncthreads();
    for (int i = tid; i < cnt; i += 256) {
        int b = ebkt[i];
        int o = atomicAdd(&lcur[b], 1);
        bbuf[(long)b * BCAP + lbase[b] + o] = entry[i];
    }
}

// ---------- stage both weight fragment arrays into LDS (linear copy) ---------------
// CTOT = total ushorts (Wfl then Wfr). 512 threads, short8 loads/stores.
template <int CTOT>
__device__ __forceinline__ void stage_weights(const ushort* __restrict__ Wfl,
                                              const ushort* __restrict__ Wfr,
                                              ushort* dst, int tid) {
    constexpr int HALF = CTOT / 2;            // ushorts per matrix
    constexpr int ITERS = (CTOT * 2) / 8192;  // 512 thr * 16B per iter
#pragma unroll
    for (int r = 0; r < ITERS; ++r) {
        int u = r * 4096 + tid * 8;           // ushort index; half uniform per r
        const ushort* s = (u < HALF) ? (Wfl + u) : (Wfr + (u - HALF));
        *(short8*)(dst + u) = *(const short8*)s;
    }
}

// ---------- dual projection body: p = fp8(X@Wl), q = bf16(X@Wr + b) ----------------
// Operand-swapped MFMA: D = Wfrag(A) * Xfrag(B) => lane holds 4 consecutive output
// cols of one node per ct => p packs to one dword (4xfp8), q to 8B (4xbf16).
// 512 threads, 8 waves x 16 rows; weights read from LDS (wsm), staged here.
template <int COLS, bool F32IN>
__device__ __forceinline__ void proj_body(int bid, int tid,
                            const void* __restrict__ xin,
                            const ushort* __restrict__ Wfl, const ushort* __restrict__ Wfr,
                            const float* __restrict__ bias,
                            unsigned char* __restrict__ p8, ushort* __restrict__ q, int N,
                            ushort* wsm) {
    constexpr int CT = COLS / 16;
    stage_weights<2 * COLS * 128>(Wfl, Wfr, wsm, tid);
    __syncthreads();
    const ushort* Wl = wsm;                  // LDS, linear = global Wf layout
    const ushort* Wr = wsm + COLS * 128;

    int wave = tid >> 6, lane = tid & 63;
    int quad = lane >> 4, m = lane & 15;
    long row0 = (long)bid * 128 + wave * 16;
    long node = row0 + m;
    long arow = (node < N) ? node : (N - 1);

    f32x4 accp[CT], accq[CT];
#pragma unroll
    for (int ct = 0; ct < CT; ++ct) { accp[ct] = (f32x4)0.0f; accq[ct] = (f32x4)0.0f; }

#pragma unroll
    for (int kk = 0; kk < 128; kk += 32) {
        short8 b;                            // B-frag: B[k][n=lane&15] = x[node][k]
        if (F32IN) {
            const float* xf = (const float*)xin + arow * 128 + kk + quad * 8;
            float4 f0 = *(const float4*)xf;
            float4 f1 = *(const float4*)(xf + 4);
            b[0] = (short)f2bf(f0.x); b[1] = (short)f2bf(f0.y);
            b[2] = (short)f2bf(f0.z); b[3] = (short)f2bf(f0.w);
            b[4] = (short)f2bf(f1.x); b[5] = (short)f2bf(f1.y);
            b[6] = (short)f2bf(f1.z); b[7] = (short)f2bf(f1.w);
        } else {
            b = *(const short8*)((const ushort*)xin + arow * 128 + kk + quad * 8);
        }
        int kc = (kk >> 3) + quad;
#pragma unroll
        for (int ct = 0; ct < CT; ++ct) {
            int boff = ((ct * 16 + kc) * 16 + m) * 8;      // 32-bit LDS addressing
            short8 al = *(const short8*)(Wl + boff);       // ds_read_b128
            short8 ar = *(const short8*)(Wr + boff);
            accp[ct] = __builtin_amdgcn_mfma_f32_16x16x32_bf16(al, b, accp[ct], 0, 0, 0);
            accq[ct] = __builtin_amdgcn_mfma_f32_16x16x32_bf16(ar, b, accq[ct], 0, 0, 0);
        }
    }

    if (node < N) {
#pragma unroll
        for (int ct = 0; ct < CT; ++ct) {
            int c0 = ct * 16 + quad * 4;
            float4 bv = *(const float4*)(bias + c0);
            float q0 = accq[ct][0] + bv.x, q1 = accq[ct][1] + bv.y;
            float q2 = accq[ct][2] + bv.z, q3 = accq[ct][3] + bv.w;
            unsigned w = (unsigned)__builtin_amdgcn_cvt_pk_fp8_f32(accp[ct][0], accp[ct][1], 0, false);
            w = (unsigned)__builtin_amdgcn_cvt_pk_fp8_f32(accp[ct][2], accp[ct][3], (int)w, true);
            *(unsigned*)(p8 + node * COLS + c0) = w;
            uint2 qw; qw.x = pk4bf(q0, q1); qw.y = pk4bf(q2, q3);
            *(uint2*)(q + node * COLS + c0) = qw;
        }
    }
}

// ---------- K2: build_csr (blocks 0..NB, bucket-local row_start) || proj1 ----------
// 512 threads. Dynamic LDS (64KB): proj blocks stage weights; CSR blocks use 4KB.
__global__ void __launch_bounds__(512, 4)
k2_csr_proj1(const unsigned* __restrict__ bbuf, const int* __restrict__ bcount,
             int* __restrict__ row_start, int* __restrict__ degw,
             float* __restrict__ inv_deg, int* __restrict__ ssrc, int NBcsr, int N,
             const float* __restrict__ x,
             const ushort* __restrict__ Wfl, const ushort* __restrict__ Wfr,
             const float* __restrict__ bias,
             unsigned char* __restrict__ p8, ushort* __restrict__ q) {
    extern __shared__ char smem[];
    int tid = threadIdx.x;
    if ((int)blockIdx.x >= NBcsr) {
        proj_body<128, true>((int)blockIdx.x - NBcsr, tid, x, Wfl, Wfr, bias, p8, q, N,
                             (ushort*)smem);
        return;
    }
    int* sdeg = (int*)smem;           // [512]
    int* lcur = sdeg + NPB;           // [512]
    int* wsum = lcur + NPB;           // [8]
    int b = blockIdx.x;
    int node0 = b * NPB;
    sdeg[tid] = 0;
    __syncthreads();
    int cnt = bcount[b];
    long base = (long)b * BCAP;
    const unsigned* bb = bbuf + base;
    int nv = cnt >> 2;
    for (int t = tid; t < nv; t += 512) {          // uint4-vectorized histogram
        uint4 e = ((const uint4*)bb)[t];
        atomicAdd(&sdeg[e.x & 511], 1);
        atomicAdd(&sdeg[e.y & 511], 1);
        atomicAdd(&sdeg[e.z & 511], 1);
        atomicAdd(&sdeg[e.w & 511], 1);
    }
    for (int i = (nv << 2) + tid; i < cnt; i += 512)
        atomicAdd(&sdeg[bb[i] & 511], 1);
    __syncthreads();
    int lane = tid & 63, wv = tid >> 6;
    int c0 = sdeg[tid];
    int v = c0;                                     // wave-shuffle inclusive scan
#pragma unroll
    for (int o = 1; o < 64; o <<= 1) {
        int t = __shfl_up(v, o);
        if (lane >= o) v += t;
    }
    if (lane == 63) wsum[wv] = v;
    __syncthreads();
    int add = 0;
    for (int w = 0; w < wv; ++w) add += wsum[w];
    int rs0 = v + add - c0;                         // bucket-local exclusive prefix
    lcur[tid] = rs0;
    if (node0 + tid < N) {
        row_start[node0 + tid] = (int)(base + rs0);
        degw[node0 + tid] = c0;
        inv_deg[node0 + tid] = 1.0f / (float)(c0 > 1 ? c0 : 1);
    }
    __syncthreads();
    for (int t = tid; t < nv; t += 512) {          // uint4-vectorized scatter
        uint4 e = ((const uint4*)bb)[t];
        int p0 = atomicAdd(&lcur[e.x & 511], 1);
        int p1 = atomicAdd(&lcur[e.y & 511], 1);
        int p2 = atomicAdd(&lcur[e.z & 511], 1);
        int p3 = atomicAdd(&lcur[e.w & 511], 1);
        ssrc[base + p0] = (int)(e.x >> 9);
        ssrc[base + p1] = (int)(e.y >> 9);
        ssrc[base + p2] = (int)(e.z >> 9);
        ssrc[base + p3] = (int)(e.w >> 9);
    }
    for (int i = (nv << 2) + tid; i < cnt; i += 512) {
        unsigned w = bb[i];
        int pos = atomicAdd(&lcur[w & 511], 1);
        ssrc[base + pos] = (int)(w >> 9);
    }
}

// ---------- layer-1 aggregate (r5 verbatim): h = bf16(relu(mean_nbr(p) + q)) -------
// One wave per node; 16 lanes per edge, 8B/lane: one instr = 4 rows (512B).
__global__ void __launch_bounds__(256)
agg_relu_kernel(const unsigned char* __restrict__ p8,  // N x 128 fp8
                const ushort* __restrict__ q,          // N x 128 bf16
                const int* __restrict__ ssrc,
                const int* __restrict__ row_start,
                const int* __restrict__ deg,
                const float* __restrict__ inv_deg,
                ushort* __restrict__ hb, int N) {
    int wave = threadIdx.x >> 6, lane = threadIdx.x & 63;
    int n = blockIdx.x * 4 + wave;
    if (n >= N) return;
    int g = lane >> 4, lm = lane & 15;             // edge slot / cols lm*8..lm*8+7
    int start = row_start[n], d = deg[n];
    const int* sp = ssrc + start;
    const unsigned char* pb = p8 + lm * 8;
    f32x2 a0 = (f32x2)0.f, a1 = (f32x2)0.f, a2 = (f32x2)0.f, a3 = (f32x2)0.f;
    int j = 0;
    for (; j + 16 <= d; j += 16) {                 // 4 row loads = 16 edges in flight
        int s0 = sp[j + g], s1 = sp[j + 4 + g], s2 = sp[j + 8 + g], s3 = sp[j + 12 + g];
        uint2 v0 = *(const uint2*)(pb + (long)s0 * 128);
        uint2 v1 = *(const uint2*)(pb + (long)s1 * 128);
        uint2 v2 = *(const uint2*)(pb + (long)s2 * 128);
        uint2 v3 = *(const uint2*)(pb + (long)s3 * 128);
#pragma unroll
        for (int t = 0; t < 4; ++t) {
            uint2 vv = (t == 0) ? v0 : (t == 1) ? v1 : (t == 2) ? v2 : v3;
            a0 += __builtin_amdgcn_cvt_pk_f32_fp8((int)vv.x, false);
            a1 += __builtin_amdgcn_cvt_pk_f32_fp8((int)vv.x, true);
            a2 += __builtin_amdgcn_cvt_pk_f32_fp8((int)vv.y, false);
            a3 += __builtin_amdgcn_cvt_pk_f32_fp8((int)vv.y, true);
        }
    }
    for (; j < d; j += 4) {                        // predicated tail, 4 edges/iter
        int idx = j + g;
        int s = sp[idx < d ? idx : j];
        uint2 vv = *(const uint2*)(pb + (long)s * 128);
        if (idx < d) {
            a0 += __builtin_amdgcn_cvt_pk_f32_fp8((int)vv.x, false);
            a1 += __builtin_amdgcn_cvt_pk_f32_fp8((int)vv.x, true);
            a2 += __builtin_amdgcn_cvt_pk_f32_fp8((int)vv.y, false);
            a3 += __builtin_amdgcn_cvt_pk_f32_fp8((int)vv.y, true);
        }
    }
    a0 += shflx2(a0, 16); a1 += shflx2(a1, 16);
    a2 += shflx2(a2, 16); a3 += shflx2(a3, 16);
    a0 += shflx2(a0, 32); a1 += shflx2(a1, 32);
    a2 += shflx2(a2, 32); a3 += shflx2(a3, 32);
    if (g == 0) {
        float iv = inv_deg[n];
        uint4 qv = *(const uint4*)(q + (long)n * 128 + lm * 8);
        float h0 = fmaxf(a0[0] * iv + bflo(qv.x), 0.f);
        float h1 = fmaxf(a0[1] * iv + bfhi(qv.x), 0.f);
        float h2 = fmaxf(a1[0] * iv + bflo(qv.y), 0.f);
        float h3 = fmaxf(a1[1] * iv + bfhi(qv.y), 0.f);
        float h4 = fmaxf(a2[0] * iv + bflo(qv.z), 0.f);
        float h5 = fmaxf(a2[1] * iv + bfhi(qv.z), 0.f);
        float h6 = fmaxf(a3[0] * iv + bflo(qv.w), 0.f);
        float h7 = fmaxf(a3[1] * iv + bfhi(qv.w), 0.f);
        uint4 hw;
        hw.x = pk4bf(h0, h1); hw.y = pk4bf(h2, h3);
        hw.z = pk4bf(h4, h5); hw.w = pk4bf(h6, h7);
        *(uint4*)(hb + (long)n * 128 + lm * 8) = hw;
    }
}

// ---------- proj2 (standalone, 512 threads, 32KB static LDS for weights) -----------
__global__ void __launch_bounds__(512, 4)
proj2_kernel(const ushort* __restrict__ hb,
             const ushort* __restrict__ Wfl, const ushort* __restrict__ Wfr,
             const float* __restrict__ bias,
             unsigned char* __restrict__ u8, ushort* __restrict__ v, int N) {
    __shared__ ushort wsm[2 * 64 * 128];   // 32 KB
    proj_body<64, false>((int)blockIdx.x, (int)threadIdx.x, hb, Wfl, Wfr, bias, u8, v, N,
                         wsm);
}

// ---------- layer-2 aggregate + log_softmax (r5 verbatim) --------------------------
// One wave per node; 8 lanes per edge, 8B/lane: one instr = 8 rows (512B).
__global__ void __launch_bounds__(256)
agg_lsm_kernel(const unsigned char* __restrict__ u8,   // N x 64 fp8
               const ushort* __restrict__ v,           // N x 64 bf16
               const int* __restrict__ ssrc,
               const int* __restrict__ row_start,
               const int* __restrict__ deg,
               const float* __restrict__ inv_deg,
               float* __restrict__ out, int N) {
    int wave = threadIdx.x >> 6, lane = threadIdx.x & 63;
    int n = blockIdx.x * 4 + wave;
    if (n >= N) return;
    int g = lane >> 3, lm = lane & 7;              // edge slot / cols lm*8..lm*8+7
    int start = row_start[n], d = deg[n];
    const int* sp = ssrc + start;
    const unsigned char* ub = u8 + lm * 8;
    f32x2 a0 = (f32x2)0.f, a1 = (f32x2)0.f, a2 = (f32x2)0.f, a3 = (f32x2)0.f;
    int j = 0;
    for (; j + 16 <= d; j += 16) {                 // 2 row loads = 16 edges in flight
        int s0 = sp[j + g], s1 = sp[j + 8 + g];
        uint2 v0 = *(const uint2*)(ub + (long)s0 * 64);
        uint2 v1 = *(const uint2*)(ub + (long)s1 * 64);
#pragma unroll
        for (int t = 0; t < 2; ++t) {
            uint2 vv = (t == 0) ? v0 : v1;
            a0 += __builtin_amdgcn_cvt_pk_f32_fp8((int)vv.x, false);
            a1 += __builtin_amdgcn_cvt_pk_f32_fp8((int)vv.x, true);
            a2 += __builtin_amdgcn_cvt_pk_f32_fp8((int)vv.y, false);
            a3 += __builtin_amdgcn_cvt_pk_f32_fp8((int)vv.y, true);
        }
    }
    for (; j < d; j += 8) {                        // predicated tail, 8 edges/iter
        int idx = j + g;
        int s = sp[idx < d ? idx : j];
        uint2 vv = *(const uint2*)(ub + (long)s * 64);
        if (idx < d) {
            a0 += __builtin_amdgcn_cvt_pk_f32_fp8((int)vv.x, false);
            a1 += __builtin_amdgcn_cvt_pk_f32_fp8((int)vv.x, true);
            a2 += __builtin_amdgcn_cvt_pk_f32_fp8((int)vv.y, false);
            a3 += __builtin_amdgcn_cvt_pk_f32_fp8((int)vv.y, true);
        }
    }
    a0 += shflx2(a0, 8);  a1 += shflx2(a1, 8);  a2 += shflx2(a2, 8);  a3 += shflx2(a3, 8);
    a0 += shflx2(a0, 16); a1 += shflx2(a1, 16); a2 += shflx2(a2, 16); a3 += shflx2(a3, 16);
    a0 += shflx2(a0, 32); a1 += shflx2(a1, 32); a2 += shflx2(a2, 32); a3 += shflx2(a3, 32);

    float iv = inv_deg[n];
    uint4 vv = *(const uint4*)(v + (long)n * 64 + lm * 8);
    float z0 = a0[0] * iv + bflo(vv.x), z1 = a0[1] * iv + bfhi(vv.x);
    float z2 = a1[0] * iv + bflo(vv.y), z3 = a1[1] * iv + bfhi(vv.y);
    float z4 = a2[0] * iv + bflo(vv.z), z5 = a2[1] * iv + bfhi(vv.z);
    float z6 = a3[0] * iv + bflo(vv.w), z7 = a3[1] * iv + bfhi(vv.w);
    float mx = fmaxf(fmaxf(fmaxf(z0, z1), fmaxf(z2, z3)),
                     fmaxf(fmaxf(z4, z5), fmaxf(z6, z7)));
#pragma unroll
    for (int o = 4; o > 0; o >>= 1) mx = fmaxf(mx, __shfl_xor(mx, o));   // over lm bits
    float e = (__expf(z0 - mx) + __expf(z1 - mx)) + (__expf(z2 - mx) + __expf(z3 - mx)) +
              (__expf(z4 - mx) + __expf(z5 - mx)) + (__expf(z6 - mx) + __expf(z7 - mx));
#pragma unroll
    for (int o = 4; o > 0; o >>= 1) e += __shfl_xor(e, o);
    float ls = mx + __logf(e);
    if (g == 0) {                                  // 8 lanes store 8 floats each
        float4 o0, o1;
        o0.x = z0 - ls; o0.y = z1 - ls; o0.z = z2 - ls; o0.w = z3 - ls;
        o1.x = z4 - ls; o1.y = z5 - ls; o1.z = z6 - ls; o1.w = z7 - ls;
        *(float4*)(out + (long)n * 64 + lm * 8) = o0;
        *(float4*)(out + (long)n * 64 + lm * 8 + 4) = o1;
    }
}

// -----------------------------------------------------------------------------------
extern "C" void kernel_launch(void* const* d_in, const int* in_sizes, int n_in,
                              void* d_out, int out_size, void* d_ws, size_t ws_size,
                              hipStream_t stream) {
    const float* x   = (const float*)d_in[0];
    const int*   ei  = (const int*)d_in[1];
    const float* Wl1 = (const float*)d_in[2];
    const float* Wr1 = (const float*)d_in[3];
    const float* b1  = (const float*)d_in[4];
    const float* Wl2 = (const float*)d_in[5];
    const float* Wr2 = (const float*)d_in[6];
    const float* b2  = (const float*)d_in[7];

    const int N = in_sizes[0] / 128;
    const int E = in_sizes[1] / 2;
    const int* src = ei;
    const int* dst = ei + E;
    const int NB = (N + NPB - 1) / NPB;             // 196 buckets for N=100000
    const int NSC = (E + CHUNK - 1) / CHUNK;        // 196 scatter blocks

    size_t off = 0;
    auto take = [&](size_t nbytes) -> void* {
        void* ptr = (void*)((char*)d_ws + off);
        off += (nbytes + 255) & ~(size_t)255;
        return ptr;
    };
    int*      bcount    = (int*)take((size_t)NB * 4);
    unsigned* bbuf      = (unsigned*)take((size_t)NB * BCAP * 4);   // 12.8 MB
    int*      row_start = (int*)take((size_t)N * 4);
    int*      degw      = (int*)take((size_t)N * 4);
    float*    inv_deg   = (float*)take((size_t)N * 4);
    int*      ssrc      = (int*)take((size_t)NB * BCAP * 4);        // 12.8 MB (bucket-strided)
    unsigned char* p8   = (unsigned char*)take((size_t)N * 128);    // reused as u8
    ushort*   q         = (ushort*)take((size_t)N * 128 * 2);       // reused as v
    ushort*   hb        = (ushort*)take((size_t)N * 128 * 2);
    ushort*   Wf_l1     = (ushort*)take(128 * 128 * 2);
    ushort*   Wf_r1     = (ushort*)take(128 * 128 * 2);
    ushort*   Wf_l2     = (ushort*)take(64 * 128 * 2);
    ushort*   Wf_r2     = (ushort*)take(64 * 128 * 2);
    unsigned char* u8 = p8;   // p dead after agg_relu
    ushort*        v  = q;    // q dead after agg_relu
    (void)ws_size; (void)n_in; (void)out_size;

    static bool attr_set = false;                   // allow 64KB dynamic LDS for k2
    if (!attr_set) {
        hipFuncSetAttribute((const void*)k2_csr_proj1,
                            hipFuncAttributeMaxDynamicSharedMemorySize, 65536);
        attr_set = true;
    }

    hipMemsetAsync(bcount, 0, (size_t)NB * 4, stream);

    // K1: scatter || weight repack (independent)
    k1_scatter_cvtw<<<NSC + 192, 256, 0, stream>>>(src, dst, bcount, bbuf, E, NSC,
                                                   Wl1, Wr1, Wl2, Wr2,
                                                   Wf_l1, Wf_r1, Wf_l2, Wf_r2);

    // K2: build_csr (vectorized, shuffle-scan) || proj1 (LDS-staged weights)
    int P1 = (N + 127) / 128;
    k2_csr_proj1<<<NB + P1, 512, 65536, stream>>>(bbuf, bcount, row_start, degw, inv_deg,
                                                  ssrc, NB, N, x, Wf_l1, Wf_r1, b1, p8, q);

    // layer 1 aggregate
    agg_relu_kernel<<<(N + 3) / 4, 256, 0, stream>>>(p8, q, ssrc, row_start, degw, inv_deg, hb, N);

    // layer 2
    proj2_kernel<<<(N + 127) / 128, 512, 0, stream>>>(hb, Wf_l2, Wf_r2, b2, u8, v, N);
    agg_lsm_kernel<<<(N + 3) / 4, 256, 0, stream>>>(u8, v, ssrc, row_start, degw, inv_deg,
                                                    (float*)d_out, N);
}

// Round 2
// 251.925 us; speedup vs baseline: 1.1323x; 1.0338x over previous
//
#include <hip/hip_runtime.h>
#include <hip/hip_bf16.h>

// GraphSAGE 2-layer, N=100K, E=1.6M, 128->128(relu)->64, log_softmax. fp32 in/out.
//
//   p = fp8(x@Wl1); q = bf16(x@Wr1 + b1)      (MFMA proj, operand-swapped, LDS-staged W)
//   h = bf16(relu(mean_nbr(p) + q))            (gather: 32 lanes/edge, 4B)
//   u = fp8(h@Wl2); v = bf16(h@Wr2 + b2)       (MFMA proj, LDS-staged W)
//   out = log_softmax(mean_nbr(u) + v)         (gather: 16 lanes/edge, 4B)
//
// r10: agg kernels were issue+latency bound (VALUBusy 46%, HBM 29%, occ 67%).
//  - 32 lanes/edge (relu) / 16 lanes/edge (lsm): 8 gathers in flight (2x MLP),
//    merge 16->4 shuffles, epilogue cols/lane halved, active lanes doubled.
//  - rsd[] packs row_start+deg -> one int2 load; inv_deg + q/v row loads hoisted
//    to top of wave so latency hides under gather loop.
//  - 8/4-edge mid-tier chunks before 2-edge predicated tail.
//  - v_cvt_pk_bf16_f32 asm replaces manual f2bf pair packing in all hot paths.

typedef __attribute__((ext_vector_type(8))) short short8;   // 8 x bf16 = 4 VGPRs
typedef __attribute__((ext_vector_type(4))) float f32x4;
typedef __attribute__((ext_vector_type(2))) float f32x2;

#define NPB 512          // nodes per bucket (dst >> 9)
#define BCAP 16384       // edge capacity per bucket (mean 8163)
#define CHUNK 8192       // edges per bucket_scatter block

__device__ __forceinline__ ushort f2bf(float f) {           // round-to-nearest-even
    unsigned u = __float_as_uint(f);
    return (ushort)((u + 0x7fff + ((u >> 16) & 1)) >> 16);
}
__device__ __forceinline__ float bflo(unsigned v) { return __uint_as_float(v << 16); }
__device__ __forceinline__ float bfhi(unsigned v) { return __uint_as_float(v & 0xffff0000u); }
__device__ __forceinline__ unsigned pk4bf(float a, float b) {   // 1 VOP3 (RNE)
    unsigned r;
    asm("v_cvt_pk_bf16_f32 %0, %1, %2" : "=v"(r) : "v"(a), "v"(b));
    return r;
}
__device__ __forceinline__ f32x2 shflx2(f32x2 v, int m) {
    f32x2 r; r[0] = __shfl_xor(v[0], m); r[1] = __shfl_xor(v[1], m); return r;
}

// ---------- weight repack into MFMA fragment order ---------------------------------
// Wf idx = ((ct*16 + kc)*16 + m)*8 + j holds W[k=kc*8+j][c=ct*16+m]
__device__ __forceinline__ void wfrag_one(const float* W, ushort* Wf, int i, int COLS) {
    int j = i & 7, m = (i >> 3) & 15, kc = (i >> 7) & 15, ct = i >> 11;
    Wf[i] = f2bf(W[(kc * 8 + j) * COLS + ct * 16 + m]);
}

// ---------- K1: bucket_scatter (blocks 0..NSC) || cvt_w (rest) ---------------------
__global__ void __launch_bounds__(256)
k1_scatter_cvtw(const int* __restrict__ src, const int* __restrict__ dst,
                int* __restrict__ bcount, unsigned* __restrict__ bbuf, int E, int NSC,
                const float* __restrict__ Wl1, const float* __restrict__ Wr1,
                const float* __restrict__ Wl2, const float* __restrict__ Wr2,
                ushort* __restrict__ Wf_l1, ushort* __restrict__ Wf_r1,
                ushort* __restrict__ Wf_l2, ushort* __restrict__ Wf_r2) {
    int tid = threadIdx.x;
    if ((int)blockIdx.x >= NSC) {
        int i = ((int)blockIdx.x - NSC) * 256 + tid;   // 49152 total
        if (i < 16384)       wfrag_one(Wl1, Wf_l1, i, 128);
        else if (i < 32768)  wfrag_one(Wr1, Wf_r1, i - 16384, 128);
        else if (i < 40960)  wfrag_one(Wl2, Wf_l2, i - 32768, 64);
        else if (i < 49152)  wfrag_one(Wr2, Wf_r2, i - 40960, 64);
        return;
    }
    __shared__ unsigned entry[CHUNK];        // 32 KB: (src<<9)|(dst&511)
    __shared__ unsigned char ebkt[CHUNK];    // 8 KB: bucket id (dst>>9 < 256)
    __shared__ int lhist[256], lbase[256], lcur[256];
    lhist[tid] = 0;
    __syncthreads();
    int e0 = blockIdx.x * CHUNK;
    int cnt = min(CHUNK, E - e0);
    int nv = cnt >> 2;
    for (int t = tid; t < nv; t += 256) {
        int4 d4 = ((const int4*)(dst + e0))[t];
        int4 s4 = ((const int4*)(src + e0))[t];
        int i = t * 4;
        int b0 = d4.x >> 9, b1 = d4.y >> 9, b2 = d4.z >> 9, b3 = d4.w >> 9;
        entry[i + 0] = ((unsigned)s4.x << 9) | (unsigned)(d4.x & 511);
        entry[i + 1] = ((unsigned)s4.y << 9) | (unsigned)(d4.y & 511);
        entry[i + 2] = ((unsigned)s4.z << 9) | (unsigned)(d4.z & 511);
        entry[i + 3] = ((unsigned)s4.w << 9) | (unsigned)(d4.w & 511);
        ebkt[i + 0] = (unsigned char)b0; ebkt[i + 1] = (unsigned char)b1;
        ebkt[i + 2] = (unsigned char)b2; ebkt[i + 3] = (unsigned char)b3;
        atomicAdd(&lhist[b0], 1); atomicAdd(&lhist[b1], 1);
        atomicAdd(&lhist[b2], 1); atomicAdd(&lhist[b3], 1);
    }
    for (int i = (nv << 2) + tid; i < cnt; i += 256) {
        int d = dst[e0 + i], s = src[e0 + i];
        int b = d >> 9;
        entry[i] = ((unsigned)s << 9) | (unsigned)(d & 511);
        ebkt[i] = (unsigned char)b;
        atomicAdd(&lhist[b], 1);
    }
    __syncthreads();
    int h = lhist[tid];
    lbase[tid] = (h > 0) ? atomicAdd(&bcount[tid], h) : 0;
    lcur[tid] = 0;
    __syncthreads();
    for (int i = tid; i < cnt; i += 256) {
        int b = ebkt[i];
        int o = atomicAdd(&lcur[b], 1);
        bbuf[(long)b * BCAP + lbase[b] + o] = entry[i];
    }
}

// ---------- stage both weight fragment arrays into LDS (linear copy) ---------------
template <int CTOT>
__device__ __forceinline__ void stage_weights(const ushort* __restrict__ Wfl,
                                              const ushort* __restrict__ Wfr,
                                              ushort* dst, int tid) {
    constexpr int HALF = CTOT / 2;            // ushorts per matrix
    constexpr int ITERS = (CTOT * 2) / 8192;  // 512 thr * 16B per iter
#pragma unroll
    for (int r = 0; r < ITERS; ++r) {
        int u = r * 4096 + tid * 8;           // ushort index; half uniform per r
        const ushort* s = (u < HALF) ? (Wfl + u) : (Wfr + (u - HALF));
        *(short8*)(dst + u) = *(const short8*)s;
    }
}

// ---------- dual projection body: p = fp8(X@Wl), q = bf16(X@Wr + b) ----------------
// Operand-swapped MFMA: D = Wfrag(A) * Xfrag(B) => lane holds 4 consecutive output
// cols of one node per ct. 512 threads, 8 waves x 16 rows; weights in LDS.
template <int COLS, bool F32IN>
__device__ __forceinline__ void proj_body(int bid, int tid,
                            const void* __restrict__ xin,
                            const ushort* __restrict__ Wfl, const ushort* __restrict__ Wfr,
                            const float* __restrict__ bias,
                            unsigned char* __restrict__ p8, ushort* __restrict__ q, int N,
                            ushort* wsm) {
    constexpr int CT = COLS / 16;
    stage_weights<2 * COLS * 128>(Wfl, Wfr, wsm, tid);
    __syncthreads();
    const ushort* Wl = wsm;                  // LDS, linear = global Wf layout
    const ushort* Wr = wsm + COLS * 128;

    int wave = tid >> 6, lane = tid & 63;
    int quad = lane >> 4, m = lane & 15;
    long row0 = (long)bid * 128 + wave * 16;
    long node = row0 + m;
    long arow = (node < N) ? node : (N - 1);

    f32x4 accp[CT], accq[CT];
#pragma unroll
    for (int ct = 0; ct < CT; ++ct) { accp[ct] = (f32x4)0.0f; accq[ct] = (f32x4)0.0f; }

#pragma unroll
    for (int kk = 0; kk < 128; kk += 32) {
        short8 b;                            // B-frag: B[k][n=lane&15] = x[node][k]
        if (F32IN) {
            const float* xf = (const float*)xin + arow * 128 + kk + quad * 8;
            float4 f0 = *(const float4*)xf;
            float4 f1 = *(const float4*)(xf + 4);
            union { short8 s; unsigned u[4]; } bu;
            bu.u[0] = pk4bf(f0.x, f0.y);
            bu.u[1] = pk4bf(f0.z, f0.w);
            bu.u[2] = pk4bf(f1.x, f1.y);
            bu.u[3] = pk4bf(f1.z, f1.w);
            b = bu.s;
        } else {
            b = *(const short8*)((const ushort*)xin + arow * 128 + kk + quad * 8);
        }
        int kc = (kk >> 3) + quad;
#pragma unroll
        for (int ct = 0; ct < CT; ++ct) {
            int boff = ((ct * 16 + kc) * 16 + m) * 8;      // 32-bit LDS addressing
            short8 al = *(const short8*)(Wl + boff);       // ds_read_b128
            short8 ar = *(const short8*)(Wr + boff);
            accp[ct] = __builtin_amdgcn_mfma_f32_16x16x32_bf16(al, b, accp[ct], 0, 0, 0);
            accq[ct] = __builtin_amdgcn_mfma_f32_16x16x32_bf16(ar, b, accq[ct], 0, 0, 0);
        }
    }

    if (node < N) {
#pragma unroll
        for (int ct = 0; ct < CT; ++ct) {
            int c0 = ct * 16 + quad * 4;
            float4 bv = *(const float4*)(bias + c0);
            float q0 = accq[ct][0] + bv.x, q1 = accq[ct][1] + bv.y;
            float q2 = accq[ct][2] + bv.z, q3 = accq[ct][3] + bv.w;
            unsigned w = (unsigned)__builtin_amdgcn_cvt_pk_fp8_f32(accp[ct][0], accp[ct][1], 0, false);
            w = (unsigned)__builtin_amdgcn_cvt_pk_fp8_f32(accp[ct][2], accp[ct][3], (int)w, true);
            *(unsigned*)(p8 + node * COLS + c0) = w;
            uint2 qw; qw.x = pk4bf(q0, q1); qw.y = pk4bf(q2, q3);
            *(uint2*)(q + node * COLS + c0) = qw;
        }
    }
}

// ---------- K2: build_csr (blocks 0..NB) || proj1 ----------------------------------
// 512 threads. Dynamic LDS (64KB): proj blocks stage weights; CSR blocks use 4KB.
__global__ void __launch_bounds__(512, 4)
k2_csr_proj1(const unsigned* __restrict__ bbuf, const int* __restrict__ bcount,
             int* __restrict__ rsd,            // [2N]: {row_start, deg} per node
             float* __restrict__ inv_deg, int* __restrict__ ssrc, int NBcsr, int N,
             const float* __restrict__ x,
             const ushort* __restrict__ Wfl, const ushort* __restrict__ Wfr,
             const float* __restrict__ bias,
             unsigned char* __restrict__ p8, ushort* __restrict__ q) {
    extern __shared__ char smem[];
    int tid = threadIdx.x;
    if ((int)blockIdx.x >= NBcsr) {
        proj_body<128, true>((int)blockIdx.x - NBcsr, tid, x, Wfl, Wfr, bias, p8, q, N,
                             (ushort*)smem);
        return;
    }
    int* sdeg = (int*)smem;           // [512]
    int* lcur = sdeg + NPB;           // [512]
    int* wsum = lcur + NPB;           // [8]
    int b = blockIdx.x;
    int node0 = b * NPB;
    sdeg[tid] = 0;
    __syncthreads();
    int cnt = bcount[b];
    long base = (long)b * BCAP;
    const unsigned* bb = bbuf + base;
    int nv = cnt >> 2;
    for (int t = tid; t < nv; t += 512) {          // uint4-vectorized histogram
        uint4 e = ((const uint4*)bb)[t];
        atomicAdd(&sdeg[e.x & 511], 1);
        atomicAdd(&sdeg[e.y & 511], 1);
        atomicAdd(&sdeg[e.z & 511], 1);
        atomicAdd(&sdeg[e.w & 511], 1);
    }
    for (int i = (nv << 2) + tid; i < cnt; i += 512)
        atomicAdd(&sdeg[bb[i] & 511], 1);
    __syncthreads();
    int lane = tid & 63, wv = tid >> 6;
    int c0 = sdeg[tid];
    int v = c0;                                     // wave-shuffle inclusive scan
#pragma unroll
    for (int o = 1; o < 64; o <<= 1) {
        int t = __shfl_up(v, o);
        if (lane >= o) v += t;
    }
    if (lane == 63) wsum[wv] = v;
    __syncthreads();
    int add = 0;
    for (int w = 0; w < wv; ++w) add += wsum[w];
    int rs0 = v + add - c0;                         // bucket-local exclusive prefix
    lcur[tid] = rs0;
    if (node0 + tid < N) {
        int2 rv; rv.x = (int)(base + rs0); rv.y = c0;
        *(int2*)(rsd + 2 * (node0 + tid)) = rv;
        inv_deg[node0 + tid] = 1.0f / (float)(c0 > 1 ? c0 : 1);
    }
    __syncthreads();
    for (int t = tid; t < nv; t += 512) {          // uint4-vectorized scatter
        uint4 e = ((const uint4*)bb)[t];
        int p0 = atomicAdd(&lcur[e.x & 511], 1);
        int p1 = atomicAdd(&lcur[e.y & 511], 1);
        int p2 = atomicAdd(&lcur[e.z & 511], 1);
        int p3 = atomicAdd(&lcur[e.w & 511], 1);
        ssrc[base + p0] = (int)(e.x >> 9);
        ssrc[base + p1] = (int)(e.y >> 9);
        ssrc[base + p2] = (int)(e.z >> 9);
        ssrc[base + p3] = (int)(e.w >> 9);
    }
    for (int i = (nv << 2) + tid; i < cnt; i += 512) {
        unsigned w = bb[i];
        int pos = atomicAdd(&lcur[w & 511], 1);
        ssrc[base + pos] = (int)(w >> 9);
    }
}

// ---------- layer-1 aggregate: h = bf16(relu(mean_nbr(p) + q)) ---------------------
// One wave per node; 32 lanes per edge, 4B/lane: 2 rows/instr, 8 gathers in flight.
__global__ void __launch_bounds__(256)
agg_relu_kernel(const unsigned char* __restrict__ p8,  // N x 128 fp8
                const ushort* __restrict__ q,          // N x 128 bf16
                const int* __restrict__ ssrc,
                const int* __restrict__ rsd,           // [2N] {row_start, deg}
                const float* __restrict__ inv_deg,
                ushort* __restrict__ hb, int N) {
    int wave = threadIdx.x >> 6, lane = threadIdx.x & 63;
    int n = blockIdx.x * 4 + wave;
    if (n >= N) return;
    int g = lane >> 5, lm = lane & 31;             // edge slot / cols lm*4..lm*4+3
    int2 rv = *(const int2*)(rsd + 2 * n);
    int start = rv.x, d = rv.y;
    float iv = inv_deg[n];                         // hoisted: hides under gathers
    uint2 qv = make_uint2(0u, 0u);
    if (g == 0) qv = *(const uint2*)(q + (long)n * 128 + lm * 4);   // hoisted
    const int* sp = ssrc + start;
    const unsigned char* pb = p8 + lm * 4;
    f32x2 a0 = (f32x2)0.f, a1 = (f32x2)0.f;
    int j = 0;
    for (; j + 16 <= d; j += 16) {                 // 8 row loads in flight
        int s0 = sp[j + g],      s1 = sp[j + 2 + g],  s2 = sp[j + 4 + g],  s3 = sp[j + 6 + g];
        int s4 = sp[j + 8 + g],  s5 = sp[j + 10 + g], s6 = sp[j + 12 + g], s7 = sp[j + 14 + g];
        unsigned v0 = *(const unsigned*)(pb + (long)s0 * 128);
        unsigned v1 = *(const unsigned*)(pb + (long)s1 * 128);
        unsigned v2 = *(const unsigned*)(pb + (long)s2 * 128);
        unsigned v3 = *(const unsigned*)(pb + (long)s3 * 128);
        unsigned v4 = *(const unsigned*)(pb + (long)s4 * 128);
        unsigned v5 = *(const unsigned*)(pb + (long)s5 * 128);
        unsigned v6 = *(const unsigned*)(pb + (long)s6 * 128);
        unsigned v7 = *(const unsigned*)(pb + (long)s7 * 128);
        a0 += __builtin_amdgcn_cvt_pk_f32_fp8((int)v0, false);
        a1 += __builtin_amdgcn_cvt_pk_f32_fp8((int)v0, true);
        a0 += __builtin_amdgcn_cvt_pk_f32_fp8((int)v1, false);
        a1 += __builtin_amdgcn_cvt_pk_f32_fp8((int)v1, true);
        a0 += __builtin_amdgcn_cvt_pk_f32_fp8((int)v2, false);
        a1 += __builtin_amdgcn_cvt_pk_f32_fp8((int)v2, true);
        a0 += __builtin_amdgcn_cvt_pk_f32_fp8((int)v3, false);
        a1 += __builtin_amdgcn_cvt_pk_f32_fp8((int)v3, true);
        a0 += __builtin_amdgcn_cvt_pk_f32_fp8((int)v4, false);
        a1 += __builtin_amdgcn_cvt_pk_f32_fp8((int)v4, true);
        a0 += __builtin_amdgcn_cvt_pk_f32_fp8((int)v5, false);
        a1 += __builtin_amdgcn_cvt_pk_f32_fp8((int)v5, true);
        a0 += __builtin_amdgcn_cvt_pk_f32_fp8((int)v6, false);
        a1 += __builtin_amdgcn_cvt_pk_f32_fp8((int)v6, true);
        a0 += __builtin_amdgcn_cvt_pk_f32_fp8((int)v7, false);
        a1 += __builtin_amdgcn_cvt_pk_f32_fp8((int)v7, true);
    }
    if (j + 8 <= d) {                              // mid-tier: 4 loads
        int s0 = sp[j + g], s1 = sp[j + 2 + g], s2 = sp[j + 4 + g], s3 = sp[j + 6 + g];
        unsigned v0 = *(const unsigned*)(pb + (long)s0 * 128);
        unsigned v1 = *(const unsigned*)(pb + (long)s1 * 128);
        unsigned v2 = *(const unsigned*)(pb + (long)s2 * 128);
        unsigned v3 = *(const unsigned*)(pb + (long)s3 * 128);
        a0 += __builtin_amdgcn_cvt_pk_f32_fp8((int)v0, false);
        a1 += __builtin_amdgcn_cvt_pk_f32_fp8((int)v0, true);
        a0 += __builtin_amdgcn_cvt_pk_f32_fp8((int)v1, false);
        a1 += __builtin_amdgcn_cvt_pk_f32_fp8((int)v1, true);
        a0 += __builtin_amdgcn_cvt_pk_f32_fp8((int)v2, false);
        a1 += __builtin_amdgcn_cvt_pk_f32_fp8((int)v2, true);
        a0 += __builtin_amdgcn_cvt_pk_f32_fp8((int)v3, false);
        a1 += __builtin_amdgcn_cvt_pk_f32_fp8((int)v3, true);
        j += 8;
    }
    if (j + 4 <= d) {                              // mid-tier: 2 loads
        int s0 = sp[j + g], s1 = sp[j + 2 + g];
        unsigned v0 = *(const unsigned*)(pb + (long)s0 * 128);
        unsigned v1 = *(const unsigned*)(pb + (long)s1 * 128);
        a0 += __builtin_amdgcn_cvt_pk_f32_fp8((int)v0, false);
        a1 += __builtin_amdgcn_cvt_pk_f32_fp8((int)v0, true);
        a0 += __builtin_amdgcn_cvt_pk_f32_fp8((int)v1, false);
        a1 += __builtin_amdgcn_cvt_pk_f32_fp8((int)v1, true);
        j += 4;
    }
    for (; j < d; j += 2) {                        // predicated tail, 2 edges/iter
        int idx = j + g;
        int s = sp[idx < d ? idx : j];
        unsigned vv = *(const unsigned*)(pb + (long)s * 128);
        if (idx < d) {
            a0 += __builtin_amdgcn_cvt_pk_f32_fp8((int)vv, false);
            a1 += __builtin_amdgcn_cvt_pk_f32_fp8((int)vv, true);
        }
    }
    a0 += shflx2(a0, 32); a1 += shflx2(a1, 32);    // single merge stage
    if (g == 0) {
        float h0 = fmaxf(a0[0] * iv + bflo(qv.x), 0.f);
        float h1 = fmaxf(a0[1] * iv + bfhi(qv.x), 0.f);
        float h2 = fmaxf(a1[0] * iv + bflo(qv.y), 0.f);
        float h3 = fmaxf(a1[1] * iv + bfhi(qv.y), 0.f);
        uint2 hw;
        hw.x = pk4bf(h0, h1); hw.y = pk4bf(h2, h3);
        *(uint2*)(hb + (long)n * 128 + lm * 4) = hw;
    }
}

// ---------- proj2 (standalone, 512 threads, 32KB static LDS for weights) -----------
__global__ void __launch_bounds__(512, 4)
proj2_kernel(const ushort* __restrict__ hb,
             const ushort* __restrict__ Wfl, const ushort* __restrict__ Wfr,
             const float* __restrict__ bias,
             unsigned char* __restrict__ u8, ushort* __restrict__ v, int N) {
    __shared__ ushort wsm[2 * 64 * 128];   // 32 KB
    proj_body<64, false>((int)blockIdx.x, (int)threadIdx.x, hb, Wfl, Wfr, bias, u8, v, N,
                         wsm);
}

// ---------- layer-2 aggregate + log_softmax ----------------------------------------
// One wave per node; 16 lanes per edge, 4B/lane: 4 rows/instr.
__global__ void __launch_bounds__(256)
agg_lsm_kernel(const unsigned char* __restrict__ u8,   // N x 64 fp8
               const ushort* __restrict__ v,           // N x 64 bf16
               const int* __restrict__ ssrc,
               const int* __restrict__ rsd,            // [2N] {row_start, deg}
               const float* __restrict__ inv_deg,
               float* __restrict__ out, int N) {
    int wave = threadIdx.x >> 6, lane = threadIdx.x & 63;
    int n = blockIdx.x * 4 + wave;
    if (n >= N) return;
    int g = lane >> 4, lm = lane & 15;             // edge slot / cols lm*4..lm*4+3
    int2 rv = *(const int2*)(rsd + 2 * n);
    int start = rv.x, d = rv.y;
    float iv = inv_deg[n];                         // hoisted
    uint2 vv2 = *(const uint2*)(v + (long)n * 64 + lm * 4);   // hoisted (one line/node)
    const int* sp = ssrc + start;
    const unsigned char* ub = u8 + lm * 4;
    f32x2 a0 = (f32x2)0.f, a1 = (f32x2)0.f;
    int j = 0;
    for (; j + 16 <= d; j += 16) {                 // 4 row loads in flight
        int s0 = sp[j + g], s1 = sp[j + 4 + g], s2 = sp[j + 8 + g], s3 = sp[j + 12 + g];
        unsigned v0 = *(const unsigned*)(ub + (long)s0 * 64);
        unsigned v1 = *(const unsigned*)(ub + (long)s1 * 64);
        unsigned v2 = *(const unsigned*)(ub + (long)s2 * 64);
        unsigned v3 = *(const unsigned*)(ub + (long)s3 * 64);
        a0 += __builtin_amdgcn_cvt_pk_f32_fp8((int)v0, false);
        a1 += __builtin_amdgcn_cvt_pk_f32_fp8((int)v0, true);
        a0 += __builtin_amdgcn_cvt_pk_f32_fp8((int)v1, false);
        a1 += __builtin_amdgcn_cvt_pk_f32_fp8((int)v1, true);
        a0 += __builtin_amdgcn_cvt_pk_f32_fp8((int)v2, false);
        a1 += __builtin_amdgcn_cvt_pk_f32_fp8((int)v2, true);
        a0 += __builtin_amdgcn_cvt_pk_f32_fp8((int)v3, false);
        a1 += __builtin_amdgcn_cvt_pk_f32_fp8((int)v3, true);
    }
    if (j + 8 <= d) {                              // mid-tier: 2 loads
        int s0 = sp[j + g], s1 = sp[j + 4 + g];
        unsigned v0 = *(const unsigned*)(ub + (long)s0 * 64);
        unsigned v1 = *(const unsigned*)(ub + (long)s1 * 64);
        a0 += __builtin_amdgcn_cvt_pk_f32_fp8((int)v0, false);
        a1 += __builtin_amdgcn_cvt_pk_f32_fp8((int)v0, true);
        a0 += __builtin_amdgcn_cvt_pk_f32_fp8((int)v1, false);
        a1 += __builtin_amdgcn_cvt_pk_f32_fp8((int)v1, true);
        j += 8;
    }
    for (; j < d; j += 4) {                        // predicated tail, 4 edges/iter
        int idx = j + g;
        int s = sp[idx < d ? idx : j];
        unsigned vv = *(const unsigned*)(ub + (long)s * 64);
        if (idx < d) {
            a0 += __builtin_amdgcn_cvt_pk_f32_fp8((int)vv, false);
            a1 += __builtin_amdgcn_cvt_pk_f32_fp8((int)vv, true);
        }
    }
    a0 += shflx2(a0, 16); a1 += shflx2(a1, 16);    // 2 merge stages
    a0 += shflx2(a0, 32); a1 += shflx2(a1, 32);

    float z0 = a0[0] * iv + bflo(vv2.x), z1 = a0[1] * iv + bfhi(vv2.x);
    float z2 = a1[0] * iv + bflo(vv2.y), z3 = a1[1] * iv + bfhi(vv2.y);
    float mx = fmaxf(fmaxf(z0, z1), fmaxf(z2, z3));
#pragma unroll
    for (int o = 8; o > 0; o >>= 1) mx = fmaxf(mx, __shfl_xor(mx, o));   // over lm bits
    float e = (__expf(z0 - mx) + __expf(z1 - mx)) + (__expf(z2 - mx) + __expf(z3 - mx));
#pragma unroll
    for (int o = 8; o > 0; o >>= 1) e += __shfl_xor(e, o);
    float ls = mx + __logf(e);
    if (g == 0) {                                  // 16 lanes store 4 floats each
        float4 o0;
        o0.x = z0 - ls; o0.y = z1 - ls; o0.z = z2 - ls; o0.w = z3 - ls;
        *(float4*)(out + (long)n * 64 + lm * 4) = o0;
    }
}

// -----------------------------------------------------------------------------------
extern "C" void kernel_launch(void* const* d_in, const int* in_sizes, int n_in,
                              void* d_out, int out_size, void* d_ws, size_t ws_size,
                              hipStream_t stream) {
    const float* x   = (const float*)d_in[0];
    const int*   ei  = (const int*)d_in[1];
    const float* Wl1 = (const float*)d_in[2];
    const float* Wr1 = (const float*)d_in[3];
    const float* b1  = (const float*)d_in[4];
    const float* Wl2 = (const float*)d_in[5];
    const float* Wr2 = (const float*)d_in[6];
    const float* b2  = (const float*)d_in[7];

    const int N = in_sizes[0] / 128;
    const int E = in_sizes[1] / 2;
    const int* src = ei;
    const int* dst = ei + E;
    const int NB = (N + NPB - 1) / NPB;             // 196 buckets for N=100000
    const int NSC = (E + CHUNK - 1) / CHUNK;        // 196 scatter blocks

    size_t off = 0;
    auto take = [&](size_t nbytes) -> void* {
        void* ptr = (void*)((char*)d_ws + off);
        off += (nbytes + 255) & ~(size_t)255;
        return ptr;
    };
    int*      bcount    = (int*)take((size_t)NB * 4);
    unsigned* bbuf      = (unsigned*)take((size_t)NB * BCAP * 4);   // 12.8 MB
    int*      rsd       = (int*)take((size_t)N * 8);                // {row_start, deg}
    float*    inv_deg   = (float*)take((size_t)N * 4);
    int*      ssrc      = (int*)take((size_t)NB * BCAP * 4);        // 12.8 MB (bucket-strided)
    unsigned char* p8   = (unsigned char*)take((size_t)N * 128);    // reused as u8
    ushort*   q         = (ushort*)take((size_t)N * 128 * 2);       // reused as v
    ushort*   hb        = (ushort*)take((size_t)N * 128 * 2);
    ushort*   Wf_l1     = (ushort*)take(128 * 128 * 2);
    ushort*   Wf_r1     = (ushort*)take(128 * 128 * 2);
    ushort*   Wf_l2     = (ushort*)take(64 * 128 * 2);
    ushort*   Wf_r2     = (ushort*)take(64 * 128 * 2);
    unsigned char* u8 = p8;   // p dead after agg_relu
    ushort*        v  = q;    // q dead after agg_relu
    (void)ws_size; (void)n_in; (void)out_size;

    static bool attr_set = false;                   // allow 64KB dynamic LDS for k2
    if (!attr_set) {
        hipFuncSetAttribute((const void*)k2_csr_proj1,
                            hipFuncAttributeMaxDynamicSharedMemorySize, 65536);
        attr_set = true;
    }

    hipMemsetAsync(bcount, 0, (size_t)NB * 4, stream);

    // K1: scatter || weight repack (independent)
    k1_scatter_cvtw<<<NSC + 192, 256, 0, stream>>>(src, dst, bcount, bbuf, E, NSC,
                                                   Wl1, Wr1, Wl2, Wr2,
                                                   Wf_l1, Wf_r1, Wf_l2, Wf_r2);

    // K2: build_csr (vectorized, shuffle-scan) || proj1 (LDS-staged weights)
    int P1 = (N + 127) / 128;
    k2_csr_proj1<<<NB + P1, 512, 65536, stream>>>(bbuf, bcount, rsd, inv_deg,
                                                  ssrc, NB, N, x, Wf_l1, Wf_r1, b1, p8, q);

    // layer 1 aggregate
    agg_relu_kernel<<<(N + 3) / 4, 256, 0, stream>>>(p8, q, ssrc, rsd, inv_deg, hb, N);

    // layer 2
    proj2_kernel<<<(N + 127) / 128, 512, 0, stream>>>(hb, Wf_l2, Wf_r2, b2, u8, v, N);
    agg_lsm_kernel<<<(N + 3) / 4, 256, 0, stream>>>(u8, v, ssrc, rsd, inv_deg,
                                                    (float*)d_out, N);
}

// Round 3
// 245.163 us; speedup vs baseline: 1.1635x; 1.0276x over previous
//
#include <hip/hip_runtime.h>
#include <hip/hip_bf16.h>

// GraphSAGE 2-layer, N=100K, E=1.6M, 128->128(relu)->64, log_softmax. fp32 in/out.
//
//   p = fp8(x@Wl1); q = bf16(x@Wr1 + b1)      (MFMA proj, operand-swapped, LDS-staged W)
//   h = bf16(relu(mean_nbr(p) + q))            (gather: 16 lanes/edge, 8B, clamped batches)
//   u = fp8(h@Wl2); v = bf16(h@Wr2 + b2)       (MFMA proj, LDS-staged W)
//   out = log_softmax(mean_nbr(u) + v)         (gather: 16 lanes/edge, 4B, clamped batches)
//
// r11: agg kernels latency-bound at the compulsory per-XCD gather floor (fetch =
// 8 XCD x table size). Remaining cost = serial memory rounds/wave: mid-tier + tail
// loops serialized idx->gather dependencies. Now: single fully-predicated 16-edge
// batch loop (indices clamped to d-1, invalid slots zeroed pre-cvt), next-iter
// index prefetch under current gathers, 32-bit byte offsets. ceil(d/16)+1 rounds.

typedef __attribute__((ext_vector_type(8))) short short8;   // 8 x bf16 = 4 VGPRs
typedef __attribute__((ext_vector_type(4))) float f32x4;
typedef __attribute__((ext_vector_type(2))) float f32x2;

#define NPB 512          // nodes per bucket (dst >> 9)
#define BCAP 16384       // edge capacity per bucket (mean 8163)
#define CHUNK 8192       // edges per bucket_scatter block

__device__ __forceinline__ ushort f2bf(float f) {           // round-to-nearest-even
    unsigned u = __float_as_uint(f);
    return (ushort)((u + 0x7fff + ((u >> 16) & 1)) >> 16);
}
__device__ __forceinline__ float bflo(unsigned v) { return __uint_as_float(v << 16); }
__device__ __forceinline__ float bfhi(unsigned v) { return __uint_as_float(v & 0xffff0000u); }
__device__ __forceinline__ unsigned pk4bf(float a, float b) {   // 1 VOP3 (RNE)
    unsigned r;
    asm("v_cvt_pk_bf16_f32 %0, %1, %2" : "=v"(r) : "v"(a), "v"(b));
    return r;
}
__device__ __forceinline__ f32x2 shflx2(f32x2 v, int m) {
    f32x2 r; r[0] = __shfl_xor(v[0], m); r[1] = __shfl_xor(v[1], m); return r;
}

// ---------- weight repack into MFMA fragment order ---------------------------------
// Wf idx = ((ct*16 + kc)*16 + m)*8 + j holds W[k=kc*8+j][c=ct*16+m]
__device__ __forceinline__ void wfrag_one(const float* W, ushort* Wf, int i, int COLS) {
    int j = i & 7, m = (i >> 3) & 15, kc = (i >> 7) & 15, ct = i >> 11;
    Wf[i] = f2bf(W[(kc * 8 + j) * COLS + ct * 16 + m]);
}

// ---------- K1: bucket_scatter (blocks 0..NSC) || cvt_w (rest) ---------------------
__global__ void __launch_bounds__(256)
k1_scatter_cvtw(const int* __restrict__ src, const int* __restrict__ dst,
                int* __restrict__ bcount, unsigned* __restrict__ bbuf, int E, int NSC,
                const float* __restrict__ Wl1, const float* __restrict__ Wr1,
                const float* __restrict__ Wl2, const float* __restrict__ Wr2,
                ushort* __restrict__ Wf_l1, ushort* __restrict__ Wf_r1,
                ushort* __restrict__ Wf_l2, ushort* __restrict__ Wf_r2) {
    int tid = threadIdx.x;
    if ((int)blockIdx.x >= NSC) {
        int i = ((int)blockIdx.x - NSC) * 256 + tid;   // 49152 total
        if (i < 16384)       wfrag_one(Wl1, Wf_l1, i, 128);
        else if (i < 32768)  wfrag_one(Wr1, Wf_r1, i - 16384, 128);
        else if (i < 40960)  wfrag_one(Wl2, Wf_l2, i - 32768, 64);
        else if (i < 49152)  wfrag_one(Wr2, Wf_r2, i - 40960, 64);
        return;
    }
    __shared__ unsigned entry[CHUNK];        // 32 KB: (src<<9)|(dst&511)
    __shared__ unsigned char ebkt[CHUNK];    // 8 KB: bucket id (dst>>9 < 256)
    __shared__ int lhist[256], lbase[256], lcur[256];
    lhist[tid] = 0;
    __syncthreads();
    int e0 = blockIdx.x * CHUNK;
    int cnt = min(CHUNK, E - e0);
    int nv = cnt >> 2;
    for (int t = tid; t < nv; t += 256) {
        int4 d4 = ((const int4*)(dst + e0))[t];
        int4 s4 = ((const int4*)(src + e0))[t];
        int i = t * 4;
        int b0 = d4.x >> 9, b1 = d4.y >> 9, b2 = d4.z >> 9, b3 = d4.w >> 9;
        entry[i + 0] = ((unsigned)s4.x << 9) | (unsigned)(d4.x & 511);
        entry[i + 1] = ((unsigned)s4.y << 9) | (unsigned)(d4.y & 511);
        entry[i + 2] = ((unsigned)s4.z << 9) | (unsigned)(d4.z & 511);
        entry[i + 3] = ((unsigned)s4.w << 9) | (unsigned)(d4.w & 511);
        ebkt[i + 0] = (unsigned char)b0; ebkt[i + 1] = (unsigned char)b1;
        ebkt[i + 2] = (unsigned char)b2; ebkt[i + 3] = (unsigned char)b3;
        atomicAdd(&lhist[b0], 1); atomicAdd(&lhist[b1], 1);
        atomicAdd(&lhist[b2], 1); atomicAdd(&lhist[b3], 1);
    }
    for (int i = (nv << 2) + tid; i < cnt; i += 256) {
        int d = dst[e0 + i], s = src[e0 + i];
        int b = d >> 9;
        entry[i] = ((unsigned)s << 9) | (unsigned)(d & 511);
        ebkt[i] = (unsigned char)b;
        atomicAdd(&lhist[b], 1);
    }
    __syncthreads();
    int h = lhist[tid];
    lbase[tid] = (h > 0) ? atomicAdd(&bcount[tid], h) : 0;
    lcur[tid] = 0;
    __syncthreads();
    for (int i = tid; i < cnt; i += 256) {
        int b = ebkt[i];
        int o = atomicAdd(&lcur[b], 1);
        bbuf[(long)b * BCAP + lbase[b] + o] = entry[i];
    }
}

// ---------- stage both weight fragment arrays into LDS (linear copy) ---------------
template <int CTOT>
__device__ __forceinline__ void stage_weights(const ushort* __restrict__ Wfl,
                                              const ushort* __restrict__ Wfr,
                                              ushort* dst, int tid) {
    constexpr int HALF = CTOT / 2;            // ushorts per matrix
    constexpr int ITERS = (CTOT * 2) / 8192;  // 512 thr * 16B per iter
#pragma unroll
    for (int r = 0; r < ITERS; ++r) {
        int u = r * 4096 + tid * 8;           // ushort index; half uniform per r
        const ushort* s = (u < HALF) ? (Wfl + u) : (Wfr + (u - HALF));
        *(short8*)(dst + u) = *(const short8*)s;
    }
}

// ---------- dual projection body: p = fp8(X@Wl), q = bf16(X@Wr + b) ----------------
// Operand-swapped MFMA: D = Wfrag(A) * Xfrag(B) => lane holds 4 consecutive output
// cols of one node per ct. 512 threads, 8 waves x 16 rows; weights in LDS.
template <int COLS, bool F32IN>
__device__ __forceinline__ void proj_body(int bid, int tid,
                            const void* __restrict__ xin,
                            const ushort* __restrict__ Wfl, const ushort* __restrict__ Wfr,
                            const float* __restrict__ bias,
                            unsigned char* __restrict__ p8, ushort* __restrict__ q, int N,
                            ushort* wsm) {
    constexpr int CT = COLS / 16;
    stage_weights<2 * COLS * 128>(Wfl, Wfr, wsm, tid);
    __syncthreads();
    const ushort* Wl = wsm;                  // LDS, linear = global Wf layout
    const ushort* Wr = wsm + COLS * 128;

    int wave = tid >> 6, lane = tid & 63;
    int quad = lane >> 4, m = lane & 15;
    long row0 = (long)bid * 128 + wave * 16;
    long node = row0 + m;
    long arow = (node < N) ? node : (N - 1);

    f32x4 accp[CT], accq[CT];
#pragma unroll
    for (int ct = 0; ct < CT; ++ct) { accp[ct] = (f32x4)0.0f; accq[ct] = (f32x4)0.0f; }

#pragma unroll
    for (int kk = 0; kk < 128; kk += 32) {
        short8 b;                            // B-frag: B[k][n=lane&15] = x[node][k]
        if (F32IN) {
            const float* xf = (const float*)xin + arow * 128 + kk + quad * 8;
            float4 f0 = *(const float4*)xf;
            float4 f1 = *(const float4*)(xf + 4);
            union { short8 s; unsigned u[4]; } bu;
            bu.u[0] = pk4bf(f0.x, f0.y);
            bu.u[1] = pk4bf(f0.z, f0.w);
            bu.u[2] = pk4bf(f1.x, f1.y);
            bu.u[3] = pk4bf(f1.z, f1.w);
            b = bu.s;
        } else {
            b = *(const short8*)((const ushort*)xin + arow * 128 + kk + quad * 8);
        }
        int kc = (kk >> 3) + quad;
#pragma unroll
        for (int ct = 0; ct < CT; ++ct) {
            int boff = ((ct * 16 + kc) * 16 + m) * 8;      // 32-bit LDS addressing
            short8 al = *(const short8*)(Wl + boff);       // ds_read_b128
            short8 ar = *(const short8*)(Wr + boff);
            accp[ct] = __builtin_amdgcn_mfma_f32_16x16x32_bf16(al, b, accp[ct], 0, 0, 0);
            accq[ct] = __builtin_amdgcn_mfma_f32_16x16x32_bf16(ar, b, accq[ct], 0, 0, 0);
        }
    }

    if (node < N) {
#pragma unroll
        for (int ct = 0; ct < CT; ++ct) {
            int c0 = ct * 16 + quad * 4;
            float4 bv = *(const float4*)(bias + c0);
            float q0 = accq[ct][0] + bv.x, q1 = accq[ct][1] + bv.y;
            float q2 = accq[ct][2] + bv.z, q3 = accq[ct][3] + bv.w;
            unsigned w = (unsigned)__builtin_amdgcn_cvt_pk_fp8_f32(accp[ct][0], accp[ct][1], 0, false);
            w = (unsigned)__builtin_amdgcn_cvt_pk_fp8_f32(accp[ct][2], accp[ct][3], (int)w, true);
            *(unsigned*)(p8 + node * COLS + c0) = w;
            uint2 qw; qw.x = pk4bf(q0, q1); qw.y = pk4bf(q2, q3);
            *(uint2*)(q + node * COLS + c0) = qw;
        }
    }
}

// ---------- K2: build_csr (blocks 0..NB) || proj1 ----------------------------------
// 512 threads. Dynamic LDS (64KB): proj blocks stage weights; CSR blocks use 4KB.
__global__ void __launch_bounds__(512, 4)
k2_csr_proj1(const unsigned* __restrict__ bbuf, const int* __restrict__ bcount,
             int* __restrict__ rsd,            // [2N]: {row_start, deg} per node
             float* __restrict__ inv_deg, int* __restrict__ ssrc, int NBcsr, int N,
             const float* __restrict__ x,
             const ushort* __restrict__ Wfl, const ushort* __restrict__ Wfr,
             const float* __restrict__ bias,
             unsigned char* __restrict__ p8, ushort* __restrict__ q) {
    extern __shared__ char smem[];
    int tid = threadIdx.x;
    if ((int)blockIdx.x >= NBcsr) {
        proj_body<128, true>((int)blockIdx.x - NBcsr, tid, x, Wfl, Wfr, bias, p8, q, N,
                             (ushort*)smem);
        return;
    }
    int* sdeg = (int*)smem;           // [512]
    int* lcur = sdeg + NPB;           // [512]
    int* wsum = lcur + NPB;           // [8]
    int b = blockIdx.x;
    int node0 = b * NPB;
    sdeg[tid] = 0;
    __syncthreads();
    int cnt = bcount[b];
    long base = (long)b * BCAP;
    const unsigned* bb = bbuf + base;
    int nv = cnt >> 2;
    for (int t = tid; t < nv; t += 512) {          // uint4-vectorized histogram
        uint4 e = ((const uint4*)bb)[t];
        atomicAdd(&sdeg[e.x & 511], 1);
        atomicAdd(&sdeg[e.y & 511], 1);
        atomicAdd(&sdeg[e.z & 511], 1);
        atomicAdd(&sdeg[e.w & 511], 1);
    }
    for (int i = (nv << 2) + tid; i < cnt; i += 512)
        atomicAdd(&sdeg[bb[i] & 511], 1);
    __syncthreads();
    int lane = tid & 63, wv = tid >> 6;
    int c0 = sdeg[tid];
    int v = c0;                                     // wave-shuffle inclusive scan
#pragma unroll
    for (int o = 1; o < 64; o <<= 1) {
        int t = __shfl_up(v, o);
        if (lane >= o) v += t;
    }
    if (lane == 63) wsum[wv] = v;
    __syncthreads();
    int add = 0;
    for (int w = 0; w < wv; ++w) add += wsum[w];
    int rs0 = v + add - c0;                         // bucket-local exclusive prefix
    lcur[tid] = rs0;
    if (node0 + tid < N) {
        int2 rv; rv.x = (int)(base + rs0); rv.y = c0;
        *(int2*)(rsd + 2 * (node0 + tid)) = rv;
        inv_deg[node0 + tid] = 1.0f / (float)(c0 > 1 ? c0 : 1);
    }
    __syncthreads();
    for (int t = tid; t < nv; t += 512) {          // uint4-vectorized scatter
        uint4 e = ((const uint4*)bb)[t];
        int p0 = atomicAdd(&lcur[e.x & 511], 1);
        int p1 = atomicAdd(&lcur[e.y & 511], 1);
        int p2 = atomicAdd(&lcur[e.z & 511], 1);
        int p3 = atomicAdd(&lcur[e.w & 511], 1);
        ssrc[base + p0] = (int)(e.x >> 9);
        ssrc[base + p1] = (int)(e.y >> 9);
        ssrc[base + p2] = (int)(e.z >> 9);
        ssrc[base + p3] = (int)(e.w >> 9);
    }
    for (int i = (nv << 2) + tid; i < cnt; i += 512) {
        unsigned w = bb[i];
        int pos = atomicAdd(&lcur[w & 511], 1);
        ssrc[base + pos] = (int)(w >> 9);
    }
}

// ---------- layer-1 aggregate: h = bf16(relu(mean_nbr(p) + q)) ---------------------
// One wave per node; 16 lanes/edge, 8B/lane. Fully-predicated 16-edge batches with
// clamped indices + next-batch index prefetch: ceil(d/16)+1 memory rounds, no tail.
__global__ void __launch_bounds__(256)
agg_relu_kernel(const unsigned char* __restrict__ p8,  // N x 128 fp8
                const ushort* __restrict__ q,          // N x 128 bf16
                const int* __restrict__ ssrc,
                const int* __restrict__ rsd,           // [2N] {row_start, deg}
                const float* __restrict__ inv_deg,
                ushort* __restrict__ hb, int N) {
    int wave = threadIdx.x >> 6, lane = threadIdx.x & 63;
    int n = blockIdx.x * 4 + wave;
    if (n >= N) return;
    int g = lane >> 4, lm = lane & 15;             // 4 edge slots / cols lm*8..lm*8+7
    int2 rv = *(const int2*)(rsd + 2 * n);
    int start = rv.x, d = rv.y;
    float iv = inv_deg[n];                         // hoisted: hides under gathers
    uint4 qv = make_uint4(0u, 0u, 0u, 0u);
    if (g == 0) qv = *(const uint4*)(q + (long)n * 128 + lm * 8);   // hoisted
    const int* sp = ssrc + start;
    const unsigned char* pb = p8 + lm * 8;
    int dm1 = (d > 0) ? d - 1 : 0;                 // clamp target (row always valid)
    f32x2 a0 = (f32x2)0.f, a1 = (f32x2)0.f, a2 = (f32x2)0.f, a3 = (f32x2)0.f;
    int s0 = sp[min(g, dm1)],      s1 = sp[min(4 + g, dm1)];
    int s2 = sp[min(8 + g, dm1)],  s3 = sp[min(12 + g, dm1)];
    for (int j = 0; j < d; j += 16) {
        uint2 v0 = *(const uint2*)(pb + (unsigned)s0 * 128u);
        uint2 v1 = *(const uint2*)(pb + (unsigned)s1 * 128u);
        uint2 v2 = *(const uint2*)(pb + (unsigned)s2 * 128u);
        uint2 v3 = *(const uint2*)(pb + (unsigned)s3 * 128u);
        int jn = j + 16;                           // prefetch next batch's indices
        s0 = sp[min(jn + g, dm1)];      s1 = sp[min(jn + 4 + g, dm1)];
        s2 = sp[min(jn + 8 + g, dm1)];  s3 = sp[min(jn + 12 + g, dm1)];
        if (j + g >= d)      { v0.x = 0u; v0.y = 0u; }   // fp8 0x00 -> 0.0
        if (j + 4 + g >= d)  { v1.x = 0u; v1.y = 0u; }
        if (j + 8 + g >= d)  { v2.x = 0u; v2.y = 0u; }
        if (j + 12 + g >= d) { v3.x = 0u; v3.y = 0u; }
        a0 += __builtin_amdgcn_cvt_pk_f32_fp8((int)v0.x, false);
        a1 += __builtin_amdgcn_cvt_pk_f32_fp8((int)v0.x, true);
        a2 += __builtin_amdgcn_cvt_pk_f32_fp8((int)v0.y, false);
        a3 += __builtin_amdgcn_cvt_pk_f32_fp8((int)v0.y, true);
        a0 += __builtin_amdgcn_cvt_pk_f32_fp8((int)v1.x, false);
        a1 += __builtin_amdgcn_cvt_pk_f32_fp8((int)v1.x, true);
        a2 += __builtin_amdgcn_cvt_pk_f32_fp8((int)v1.y, false);
        a3 += __builtin_amdgcn_cvt_pk_f32_fp8((int)v1.y, true);
        a0 += __builtin_amdgcn_cvt_pk_f32_fp8((int)v2.x, false);
        a1 += __builtin_amdgcn_cvt_pk_f32_fp8((int)v2.x, true);
        a2 += __builtin_amdgcn_cvt_pk_f32_fp8((int)v2.y, false);
        a3 += __builtin_amdgcn_cvt_pk_f32_fp8((int)v2.y, true);
        a0 += __builtin_amdgcn_cvt_pk_f32_fp8((int)v3.x, false);
        a1 += __builtin_amdgcn_cvt_pk_f32_fp8((int)v3.x, true);
        a2 += __builtin_amdgcn_cvt_pk_f32_fp8((int)v3.y, false);
        a3 += __builtin_amdgcn_cvt_pk_f32_fp8((int)v3.y, true);
    }
    a0 += shflx2(a0, 16); a1 += shflx2(a1, 16);    // merge 4 slots
    a2 += shflx2(a2, 16); a3 += shflx2(a3, 16);
    a0 += shflx2(a0, 32); a1 += shflx2(a1, 32);
    a2 += shflx2(a2, 32); a3 += shflx2(a3, 32);
    if (g == 0) {
        float h0 = fmaxf(a0[0] * iv + bflo(qv.x), 0.f);
        float h1 = fmaxf(a0[1] * iv + bfhi(qv.x), 0.f);
        float h2 = fmaxf(a1[0] * iv + bflo(qv.y), 0.f);
        float h3 = fmaxf(a1[1] * iv + bfhi(qv.y), 0.f);
        float h4 = fmaxf(a2[0] * iv + bflo(qv.z), 0.f);
        float h5 = fmaxf(a2[1] * iv + bfhi(qv.z), 0.f);
        float h6 = fmaxf(a3[0] * iv + bflo(qv.w), 0.f);
        float h7 = fmaxf(a3[1] * iv + bfhi(qv.w), 0.f);
        uint4 hw;
        hw.x = pk4bf(h0, h1); hw.y = pk4bf(h2, h3);
        hw.z = pk4bf(h4, h5); hw.w = pk4bf(h6, h7);
        *(uint4*)(hb + (long)n * 128 + lm * 8) = hw;
    }
}

// ---------- proj2 (standalone, 512 threads, 32KB static LDS for weights) -----------
__global__ void __launch_bounds__(512, 4)
proj2_kernel(const ushort* __restrict__ hb,
             const ushort* __restrict__ Wfl, const ushort* __restrict__ Wfr,
             const float* __restrict__ bias,
             unsigned char* __restrict__ u8, ushort* __restrict__ v, int N) {
    __shared__ ushort wsm[2 * 64 * 128];   // 32 KB
    proj_body<64, false>((int)blockIdx.x, (int)threadIdx.x, hb, Wfl, Wfr, bias, u8, v, N,
                         wsm);
}

// ---------- layer-2 aggregate + log_softmax ----------------------------------------
// One wave per node; 16 lanes/edge, 4B/lane. Same clamped-batch + prefetch structure.
__global__ void __launch_bounds__(256)
agg_lsm_kernel(const unsigned char* __restrict__ u8,   // N x 64 fp8
               const ushort* __restrict__ v,           // N x 64 bf16
               const int* __restrict__ ssrc,
               const int* __restrict__ rsd,            // [2N] {row_start, deg}
               const float* __restrict__ inv_deg,
               float* __restrict__ out, int N) {
    int wave = threadIdx.x >> 6, lane = threadIdx.x & 63;
    int n = blockIdx.x * 4 + wave;
    if (n >= N) return;
    int g = lane >> 4, lm = lane & 15;             // 4 edge slots / cols lm*4..lm*4+3
    int2 rv = *(const int2*)(rsd + 2 * n);
    int start = rv.x, d = rv.y;
    float iv = inv_deg[n];                         // hoisted
    uint2 vv2 = *(const uint2*)(v + (long)n * 64 + lm * 4);   // hoisted
    const int* sp = ssrc + start;
    const unsigned char* ub = u8 + lm * 4;
    int dm1 = (d > 0) ? d - 1 : 0;
    f32x2 a0 = (f32x2)0.f, a1 = (f32x2)0.f;
    int s0 = sp[min(g, dm1)],      s1 = sp[min(4 + g, dm1)];
    int s2 = sp[min(8 + g, dm1)],  s3 = sp[min(12 + g, dm1)];
    for (int j = 0; j < d; j += 16) {
        unsigned v0 = *(const unsigned*)(ub + (unsigned)s0 * 64u);
        unsigned v1 = *(const unsigned*)(ub + (unsigned)s1 * 64u);
        unsigned v2 = *(const unsigned*)(ub + (unsigned)s2 * 64u);
        unsigned v3 = *(const unsigned*)(ub + (unsigned)s3 * 64u);
        int jn = j + 16;                           // prefetch next batch's indices
        s0 = sp[min(jn + g, dm1)];      s1 = sp[min(jn + 4 + g, dm1)];
        s2 = sp[min(jn + 8 + g, dm1)];  s3 = sp[min(jn + 12 + g, dm1)];
        if (j + g >= d)      v0 = 0u;              // fp8 0x00 -> 0.0
        if (j + 4 + g >= d)  v1 = 0u;
        if (j + 8 + g >= d)  v2 = 0u;
        if (j + 12 + g >= d) v3 = 0u;
        a0 += __builtin_amdgcn_cvt_pk_f32_fp8((int)v0, false);
        a1 += __builtin_amdgcn_cvt_pk_f32_fp8((int)v0, true);
        a0 += __builtin_amdgcn_cvt_pk_f32_fp8((int)v1, false);
        a1 += __builtin_amdgcn_cvt_pk_f32_fp8((int)v1, true);
        a0 += __builtin_amdgcn_cvt_pk_f32_fp8((int)v2, false);
        a1 += __builtin_amdgcn_cvt_pk_f32_fp8((int)v2, true);
        a0 += __builtin_amdgcn_cvt_pk_f32_fp8((int)v3, false);
        a1 += __builtin_amdgcn_cvt_pk_f32_fp8((int)v3, true);
    }
    a0 += shflx2(a0, 16); a1 += shflx2(a1, 16);    // merge 4 slots
    a0 += shflx2(a0, 32); a1 += shflx2(a1, 32);

    float z0 = a0[0] * iv + bflo(vv2.x), z1 = a0[1] * iv + bfhi(vv2.x);
    float z2 = a1[0] * iv + bflo(vv2.y), z3 = a1[1] * iv + bfhi(vv2.y);
    float mx = fmaxf(fmaxf(z0, z1), fmaxf(z2, z3));
#pragma unroll
    for (int o = 8; o > 0; o >>= 1) mx = fmaxf(mx, __shfl_xor(mx, o));   // over lm bits
    float e = (__expf(z0 - mx) + __expf(z1 - mx)) + (__expf(z2 - mx) + __expf(z3 - mx));
#pragma unroll
    for (int o = 8; o > 0; o >>= 1) e += __shfl_xor(e, o);
    float ls = mx + __logf(e);
    if (g == 0) {                                  // 16 lanes store 4 floats each
        float4 o0;
        o0.x = z0 - ls; o0.y = z1 - ls; o0.z = z2 - ls; o0.w = z3 - ls;
        *(float4*)(out + (long)n * 64 + lm * 4) = o0;
    }
}

// -----------------------------------------------------------------------------------
extern "C" void kernel_launch(void* const* d_in, const int* in_sizes, int n_in,
                              void* d_out, int out_size, void* d_ws, size_t ws_size,
                              hipStream_t stream) {
    const float* x   = (const float*)d_in[0];
    const int*   ei  = (const int*)d_in[1];
    const float* Wl1 = (const float*)d_in[2];
    const float* Wr1 = (const float*)d_in[3];
    const float* b1  = (const float*)d_in[4];
    const float* Wl2 = (const float*)d_in[5];
    const float* Wr2 = (const float*)d_in[6];
    const float* b2  = (const float*)d_in[7];

    const int N = in_sizes[0] / 128;
    const int E = in_sizes[1] / 2;
    const int* src = ei;
    const int* dst = ei + E;
    const int NB = (N + NPB - 1) / NPB;             // 196 buckets for N=100000
    const int NSC = (E + CHUNK - 1) / CHUNK;        // 196 scatter blocks

    size_t off = 0;
    auto take = [&](size_t nbytes) -> void* {
        void* ptr = (void*)((char*)d_ws + off);
        off += (nbytes + 255) & ~(size_t)255;
        return ptr;
    };
    int*      bcount    = (int*)take((size_t)NB * 4);
    unsigned* bbuf      = (unsigned*)take((size_t)NB * BCAP * 4);   // 12.8 MB
    int*      rsd       = (int*)take((size_t)N * 8);                // {row_start, deg}
    float*    inv_deg   = (float*)take((size_t)N * 4);
    int*      ssrc      = (int*)take((size_t)NB * BCAP * 4);        // 12.8 MB (bucket-strided)
    unsigned char* p8   = (unsigned char*)take((size_t)N * 128);    // reused as u8
    ushort*   q         = (ushort*)take((size_t)N * 128 * 2);       // reused as v
    ushort*   hb        = (ushort*)take((size_t)N * 128 * 2);
    ushort*   Wf_l1     = (ushort*)take(128 * 128 * 2);
    ushort*   Wf_r1     = (ushort*)take(128 * 128 * 2);
    ushort*   Wf_l2     = (ushort*)take(64 * 128 * 2);
    ushort*   Wf_r2     = (ushort*)take(64 * 128 * 2);
    unsigned char* u8 = p8;   // p dead after agg_relu
    ushort*        v  = q;    // q dead after agg_relu
    (void)ws_size; (void)n_in; (void)out_size;

    static bool attr_set = false;                   // allow 64KB dynamic LDS for k2
    if (!attr_set) {
        hipFuncSetAttribute((const void*)k2_csr_proj1,
                            hipFuncAttributeMaxDynamicSharedMemorySize, 65536);
        attr_set = true;
    }

    hipMemsetAsync(bcount, 0, (size_t)NB * 4, stream);

    // K1: scatter || weight repack (independent)
    k1_scatter_cvtw<<<NSC + 192, 256, 0, stream>>>(src, dst, bcount, bbuf, E, NSC,
                                                   Wl1, Wr1, Wl2, Wr2,
                                                   Wf_l1, Wf_r1, Wf_l2, Wf_r2);

    // K2: build_csr (vectorized, shuffle-scan) || proj1 (LDS-staged weights)
    int P1 = (N + 127) / 128;
    k2_csr_proj1<<<NB + P1, 512, 65536, stream>>>(bbuf, bcount, rsd, inv_deg,
                                                  ssrc, NB, N, x, Wf_l1, Wf_r1, b1, p8, q);

    // layer 1 aggregate
    agg_relu_kernel<<<(N + 3) / 4, 256, 0, stream>>>(p8, q, ssrc, rsd, inv_deg, hb, N);

    // layer 2
    proj2_kernel<<<(N + 127) / 128, 512, 0, stream>>>(hb, Wf_l2, Wf_r2, b2, u8, v, N);
    agg_lsm_kernel<<<(N + 3) / 4, 256, 0, stream>>>(u8, v, ssrc, rsd, inv_deg,
                                                    (float*)d_out, N);
}

// Round 4
// 242.885 us; speedup vs baseline: 1.1744x; 1.0094x over previous
//
#include <hip/hip_runtime.h>
#include <hip/hip_bf16.h>

// GraphSAGE 2-layer, N=100K, E=1.6M, 128->128(relu)->64, log_softmax. fp32 in/out.
//
//   p = fp8(x@Wl1); q = bf16(x@Wr1 + b1)      (MFMA proj, operand-swapped, LDS-staged W)
//   h = bf16(relu(mean_nbr(p) + q))            (gather: 16 lanes/edge, 8B, padded lists)
//   u = fp8(h@Wl2); v = bf16(h@Wr2 + b2)       (MFMA proj, LDS-staged W)
//   out = log_softmax(mean_nbr(u) + v)         (gather: 16 lanes/edge, 4B, padded lists)
//
// r12: agg kernels were VALU-issue-bound (VALUBusy 71%); ~40% of loop VALU was
// predication (min clamps + cmp + cndmask). Now: edge lists padded to multiples of
// 16 with sentinel index N; p8/u8 row N written as zeros by proj (fp8 0x00 -> 0.0).
// Inner loops are pure load->cvt->add, and slot g owns 4 CONSECUTIVE edges so the
// 4 index loads collapse to one dwordx4. Buckets get a 16-entry sentinel tail for
// the unconditional index prefetch. rsd.y now stores the PADDED degree.

typedef __attribute__((ext_vector_type(8))) short short8;   // 8 x bf16 = 4 VGPRs
typedef __attribute__((ext_vector_type(4))) float f32x4;
typedef __attribute__((ext_vector_type(2))) float f32x2;

#define NPB 512          // nodes per bucket (dst >> 9)
#define BCAP 16384       // edge capacity per bucket (padded mean ~11.8K)
#define CHUNK 8192       // edges per bucket_scatter block

__device__ __forceinline__ ushort f2bf(float f) {           // round-to-nearest-even
    unsigned u = __float_as_uint(f);
    return (ushort)((u + 0x7fff + ((u >> 16) & 1)) >> 16);
}
__device__ __forceinline__ float bflo(unsigned v) { return __uint_as_float(v << 16); }
__device__ __forceinline__ float bfhi(unsigned v) { return __uint_as_float(v & 0xffff0000u); }
__device__ __forceinline__ unsigned pk4bf(float a, float b) {   // 1 VOP3 (RNE)
    unsigned r;
    asm("v_cvt_pk_bf16_f32 %0, %1, %2" : "=v"(r) : "v"(a), "v"(b));
    return r;
}
__device__ __forceinline__ f32x2 shflx2(f32x2 v, int m) {
    f32x2 r; r[0] = __shfl_xor(v[0], m); r[1] = __shfl_xor(v[1], m); return r;
}

// ---------- weight repack into MFMA fragment order ---------------------------------
// Wf idx = ((ct*16 + kc)*16 + m)*8 + j holds W[k=kc*8+j][c=ct*16+m]
__device__ __forceinline__ void wfrag_one(const float* W, ushort* Wf, int i, int COLS) {
    int j = i & 7, m = (i >> 3) & 15, kc = (i >> 7) & 15, ct = i >> 11;
    Wf[i] = f2bf(W[(kc * 8 + j) * COLS + ct * 16 + m]);
}

// ---------- K1: bucket_scatter (blocks 0..NSC) || cvt_w (rest) ---------------------
__global__ void __launch_bounds__(256)
k1_scatter_cvtw(const int* __restrict__ src, const int* __restrict__ dst,
                int* __restrict__ bcount, unsigned* __restrict__ bbuf, int E, int NSC,
                const float* __restrict__ Wl1, const float* __restrict__ Wr1,
                const float* __restrict__ Wl2, const float* __restrict__ Wr2,
                ushort* __restrict__ Wf_l1, ushort* __restrict__ Wf_r1,
                ushort* __restrict__ Wf_l2, ushort* __restrict__ Wf_r2) {
    int tid = threadIdx.x;
    if ((int)blockIdx.x >= NSC) {
        int i = ((int)blockIdx.x - NSC) * 256 + tid;   // 49152 total
        if (i < 16384)       wfrag_one(Wl1, Wf_l1, i, 128);
        else if (i < 32768)  wfrag_one(Wr1, Wf_r1, i - 16384, 128);
        else if (i < 40960)  wfrag_one(Wl2, Wf_l2, i - 32768, 64);
        else if (i < 49152)  wfrag_one(Wr2, Wf_r2, i - 40960, 64);
        return;
    }
    __shared__ unsigned entry[CHUNK];        // 32 KB: (src<<9)|(dst&511)
    __shared__ unsigned char ebkt[CHUNK];    // 8 KB: bucket id (dst>>9 < 256)
    __shared__ int lhist[256], lbase[256], lcur[256];
    lhist[tid] = 0;
    __syncthreads();
    int e0 = blockIdx.x * CHUNK;
    int cnt = min(CHUNK, E - e0);
    int nv = cnt >> 2;
    for (int t = tid; t < nv; t += 256) {
        int4 d4 = ((const int4*)(dst + e0))[t];
        int4 s4 = ((const int4*)(src + e0))[t];
        int i = t * 4;
        int b0 = d4.x >> 9, b1 = d4.y >> 9, b2 = d4.z >> 9, b3 = d4.w >> 9;
        entry[i + 0] = ((unsigned)s4.x << 9) | (unsigned)(d4.x & 511);
        entry[i + 1] = ((unsigned)s4.y << 9) | (unsigned)(d4.y & 511);
        entry[i + 2] = ((unsigned)s4.z << 9) | (unsigned)(d4.z & 511);
        entry[i + 3] = ((unsigned)s4.w << 9) | (unsigned)(d4.w & 511);
        ebkt[i + 0] = (unsigned char)b0; ebkt[i + 1] = (unsigned char)b1;
        ebkt[i + 2] = (unsigned char)b2; ebkt[i + 3] = (unsigned char)b3;
        atomicAdd(&lhist[b0], 1); atomicAdd(&lhist[b1], 1);
        atomicAdd(&lhist[b2], 1); atomicAdd(&lhist[b3], 1);
    }
    for (int i = (nv << 2) + tid; i < cnt; i += 256) {
        int d = dst[e0 + i], s = src[e0 + i];
        int b = d >> 9;
        entry[i] = ((unsigned)s << 9) | (unsigned)(d & 511);
        ebkt[i] = (unsigned char)b;
        atomicAdd(&lhist[b], 1);
    }
    __syncthreads();
    int h = lhist[tid];
    lbase[tid] = (h > 0) ? atomicAdd(&bcount[tid], h) : 0;
    lcur[tid] = 0;
    __syncthreads();
    for (int i = tid; i < cnt; i += 256) {
        int b = ebkt[i];
        int o = atomicAdd(&lcur[b], 1);
        bbuf[(long)b * BCAP + lbase[b] + o] = entry[i];
    }
}

// ---------- stage both weight fragment arrays into LDS (linear copy) ---------------
template <int CTOT>
__device__ __forceinline__ void stage_weights(const ushort* __restrict__ Wfl,
                                              const ushort* __restrict__ Wfr,
                                              ushort* dst, int tid) {
    constexpr int HALF = CTOT / 2;            // ushorts per matrix
    constexpr int ITERS = (CTOT * 2) / 8192;  // 512 thr * 16B per iter
#pragma unroll
    for (int r = 0; r < ITERS; ++r) {
        int u = r * 4096 + tid * 8;           // ushort index; half uniform per r
        const ushort* s = (u < HALF) ? (Wfl + u) : (Wfr + (u - HALF));
        *(short8*)(dst + u) = *(const short8*)s;
    }
}

// ---------- dual projection body: p = fp8(X@Wl), q = bf16(X@Wr + b) ----------------
// Operand-swapped MFMA: D = Wfrag(A) * Xfrag(B) => lane holds 4 consecutive output
// cols of one node per ct. 512 threads, 8 waves x 16 rows; weights in LDS.
// Writes rows 0..N: row N is the ZERO sentinel row consumed by padded gathers.
template <int COLS, bool F32IN>
__device__ __forceinline__ void proj_body(int bid, int tid,
                            const void* __restrict__ xin,
                            const ushort* __restrict__ Wfl, const ushort* __restrict__ Wfr,
                            const float* __restrict__ bias,
                            unsigned char* __restrict__ p8, ushort* __restrict__ q, int N,
                            ushort* wsm) {
    constexpr int CT = COLS / 16;
    stage_weights<2 * COLS * 128>(Wfl, Wfr, wsm, tid);
    __syncthreads();
    const ushort* Wl = wsm;                  // LDS, linear = global Wf layout
    const ushort* Wr = wsm + COLS * 128;

    int wave = tid >> 6, lane = tid & 63;
    int quad = lane >> 4, m = lane & 15;
    long row0 = (long)bid * 128 + wave * 16;
    long node = row0 + m;
    long arow = (node < N) ? node : (N - 1);

    f32x4 accp[CT], accq[CT];
#pragma unroll
    for (int ct = 0; ct < CT; ++ct) { accp[ct] = (f32x4)0.0f; accq[ct] = (f32x4)0.0f; }

#pragma unroll
    for (int kk = 0; kk < 128; kk += 32) {
        short8 b;                            // B-frag: B[k][n=lane&15] = x[node][k]
        if (F32IN) {
            const float* xf = (const float*)xin + arow * 128 + kk + quad * 8;
            float4 f0 = *(const float4*)xf;
            float4 f1 = *(const float4*)(xf + 4);
            union { short8 s; unsigned u[4]; } bu;
            bu.u[0] = pk4bf(f0.x, f0.y);
            bu.u[1] = pk4bf(f0.z, f0.w);
            bu.u[2] = pk4bf(f1.x, f1.y);
            bu.u[3] = pk4bf(f1.z, f1.w);
            b = bu.s;
        } else {
            b = *(const short8*)((const ushort*)xin + arow * 128 + kk + quad * 8);
        }
        int kc = (kk >> 3) + quad;
#pragma unroll
        for (int ct = 0; ct < CT; ++ct) {
            int boff = ((ct * 16 + kc) * 16 + m) * 8;      // 32-bit LDS addressing
            short8 al = *(const short8*)(Wl + boff);       // ds_read_b128
            short8 ar = *(const short8*)(Wr + boff);
            accp[ct] = __builtin_amdgcn_mfma_f32_16x16x32_bf16(al, b, accp[ct], 0, 0, 0);
            accq[ct] = __builtin_amdgcn_mfma_f32_16x16x32_bf16(ar, b, accq[ct], 0, 0, 0);
        }
    }

    if (node <= N) {                          // row N = zero sentinel
        unsigned msk = (node == N) ? 0u : ~0u;
#pragma unroll
        for (int ct = 0; ct < CT; ++ct) {
            int c0 = ct * 16 + quad * 4;
            float4 bv = *(const float4*)(bias + c0);
            float q0 = accq[ct][0] + bv.x, q1 = accq[ct][1] + bv.y;
            float q2 = accq[ct][2] + bv.z, q3 = accq[ct][3] + bv.w;
            unsigned w = (unsigned)__builtin_amdgcn_cvt_pk_fp8_f32(accp[ct][0], accp[ct][1], 0, false);
            w = (unsigned)__builtin_amdgcn_cvt_pk_fp8_f32(accp[ct][2], accp[ct][3], (int)w, true);
            *(unsigned*)(p8 + node * COLS + c0) = w & msk;
            uint2 qw; qw.x = pk4bf(q0, q1) & msk; qw.y = pk4bf(q2, q3) & msk;
            *(uint2*)(q + node * COLS + c0) = qw;
        }
    }
}

// ---------- K2: build_csr (blocks 0..NB) || proj1 ----------------------------------
// 512 threads. Dynamic LDS (64KB): proj blocks stage weights; CSR blocks use 4KB.
// Edge lists padded to multiples of 16 with sentinel N; 16-entry bucket tail.
__global__ void __launch_bounds__(512, 4)
k2_csr_proj1(const unsigned* __restrict__ bbuf, const int* __restrict__ bcount,
             int* __restrict__ rsd,            // [2N]: {row_start, padded_deg}
             float* __restrict__ inv_deg, int* __restrict__ ssrc, int NBcsr, int N,
             const float* __restrict__ x,
             const ushort* __restrict__ Wfl, const ushort* __restrict__ Wfr,
             const float* __restrict__ bias,
             unsigned char* __restrict__ p8, ushort* __restrict__ q) {
    extern __shared__ char smem[];
    int tid = threadIdx.x;
    if ((int)blockIdx.x >= NBcsr) {
        proj_body<128, true>((int)blockIdx.x - NBcsr, tid, x, Wfl, Wfr, bias, p8, q, N,
                             (ushort*)smem);
        return;
    }
    int* sdeg = (int*)smem;           // [512]
    int* lcur = sdeg + NPB;           // [512]
    int* wsum = lcur + NPB;           // [8]
    int b = blockIdx.x;
    int node0 = b * NPB;
    sdeg[tid] = 0;
    __syncthreads();
    int cnt = bcount[b];
    long base = (long)b * BCAP;
    const unsigned* bb = bbuf + base;
    int nv = cnt >> 2;
    for (int t = tid; t < nv; t += 512) {          // uint4-vectorized histogram
        uint4 e = ((const uint4*)bb)[t];
        atomicAdd(&sdeg[e.x & 511], 1);
        atomicAdd(&sdeg[e.y & 511], 1);
        atomicAdd(&sdeg[e.z & 511], 1);
        atomicAdd(&sdeg[e.w & 511], 1);
    }
    for (int i = (nv << 2) + tid; i < cnt; i += 512)
        atomicAdd(&sdeg[bb[i] & 511], 1);
    __syncthreads();
    int lane = tid & 63, wv = tid >> 6;
    int c0 = sdeg[tid];
    int dp = (c0 + 15) & ~15;                       // padded degree
    int v = dp;                                     // wave-shuffle inclusive scan of dp
#pragma unroll
    for (int o = 1; o < 64; o <<= 1) {
        int t = __shfl_up(v, o);
        if (lane >= o) v += t;
    }
    if (lane == 63) wsum[wv] = v;
    __syncthreads();
    int add = 0;
    for (int w = 0; w < wv; ++w) add += wsum[w];
    int rs0 = v + add - dp;                         // bucket-local exclusive prefix
    lcur[tid] = rs0;
    if (node0 + tid < N) {
        int2 rv; rv.x = (int)(base + rs0); rv.y = dp;
        *(int2*)(rsd + 2 * (node0 + tid)) = rv;
        inv_deg[node0 + tid] = 1.0f / (float)(c0 > 1 ? c0 : 1);
    }
    __syncthreads();
    for (int t = tid; t < nv; t += 512) {          // uint4-vectorized scatter
        uint4 e = ((const uint4*)bb)[t];
        int p0 = atomicAdd(&lcur[e.x & 511], 1);
        int p1 = atomicAdd(&lcur[e.y & 511], 1);
        int p2 = atomicAdd(&lcur[e.z & 511], 1);
        int p3 = atomicAdd(&lcur[e.w & 511], 1);
        ssrc[base + p0] = (int)(e.x >> 9);
        ssrc[base + p1] = (int)(e.y >> 9);
        ssrc[base + p2] = (int)(e.z >> 9);
        ssrc[base + p3] = (int)(e.w >> 9);
    }
    for (int i = (nv << 2) + tid; i < cnt; i += 512) {
        unsigned w = bb[i];
        int pos = atomicAdd(&lcur[w & 511], 1);
        ssrc[base + pos] = (int)(w >> 9);
    }
    // padding fill (disjoint from scatter ranges -> no barrier needed)
    for (int i = c0; i < dp; ++i) ssrc[base + rs0 + i] = N;
    if (tid == 511) {                               // bucket tail for prefetch overrun
        int tot = v + add;
        for (int k = 0; k < 16; ++k) ssrc[base + tot + k] = N;
    }
}

// ---------- layer-1 aggregate: h = bf16(relu(mean_nbr(p) + q)) ---------------------
// One wave per node; 16 lanes/edge, 8B/lane, slot g owns 4 consecutive edges.
// Padded lists: pure load->cvt->add, one dwordx4 index load per 16-edge batch.
__global__ void __launch_bounds__(256)
agg_relu_kernel(const unsigned char* __restrict__ p8,  // (N+1) x 128 fp8, row N = 0
                const ushort* __restrict__ q,          // (N+1) x 128 bf16
                const int* __restrict__ ssrc,
                const int* __restrict__ rsd,           // [2N] {row_start, padded_deg}
                const float* __restrict__ inv_deg,
                ushort* __restrict__ hb, int N) {
    int wave = threadIdx.x >> 6, lane = threadIdx.x & 63;
    int n = blockIdx.x * 4 + wave;
    if (n >= N) return;
    int g = lane >> 4, lm = lane & 15;             // 4 edge slots / cols lm*8..lm*8+7
    int2 rv = *(const int2*)(rsd + 2 * n);
    int start = rv.x, dp = rv.y;
    float iv = inv_deg[n];                         // hoisted: hides under gathers
    uint4 qv = make_uint4(0u, 0u, 0u, 0u);
    if (g == 0) qv = *(const uint4*)(q + (long)n * 128 + lm * 8);   // hoisted
    const int* sp = ssrc + start;
    const unsigned char* pb = p8 + lm * 8;
    f32x2 a0 = (f32x2)0.f, a1 = (f32x2)0.f, a2 = (f32x2)0.f, a3 = (f32x2)0.f;
    int4 s = *(const int4*)(sp + 4 * g);           // slot g: edges 4g..4g+3
    for (int j = 0; j < dp; j += 16) {
        uint2 v0 = *(const uint2*)(pb + (unsigned)s.x * 128u);
        uint2 v1 = *(const uint2*)(pb + (unsigned)s.y * 128u);
        uint2 v2 = *(const uint2*)(pb + (unsigned)s.z * 128u);
        uint2 v3 = *(const uint2*)(pb + (unsigned)s.w * 128u);
        s = *(const int4*)(sp + j + 16 + 4 * g);   // prefetch next batch (tail-safe)
        a0 += __builtin_amdgcn_cvt_pk_f32_fp8((int)v0.x, false);
        a1 += __builtin_amdgcn_cvt_pk_f32_fp8((int)v0.x, true);
        a2 += __builtin_amdgcn_cvt_pk_f32_fp8((int)v0.y, false);
        a3 += __builtin_amdgcn_cvt_pk_f32_fp8((int)v0.y, true);
        a0 += __builtin_amdgcn_cvt_pk_f32_fp8((int)v1.x, false);
        a1 += __builtin_amdgcn_cvt_pk_f32_fp8((int)v1.x, true);
        a2 += __builtin_amdgcn_cvt_pk_f32_fp8((int)v1.y, false);
        a3 += __builtin_amdgcn_cvt_pk_f32_fp8((int)v1.y, true);
        a0 += __builtin_amdgcn_cvt_pk_f32_fp8((int)v2.x, false);
        a1 += __builtin_amdgcn_cvt_pk_f32_fp8((int)v2.x, true);
        a2 += __builtin_amdgcn_cvt_pk_f32_fp8((int)v2.y, false);
        a3 += __builtin_amdgcn_cvt_pk_f32_fp8((int)v2.y, true);
        a0 += __builtin_amdgcn_cvt_pk_f32_fp8((int)v3.x, false);
        a1 += __builtin_amdgcn_cvt_pk_f32_fp8((int)v3.x, true);
        a2 += __builtin_amdgcn_cvt_pk_f32_fp8((int)v3.y, false);
        a3 += __builtin_amdgcn_cvt_pk_f32_fp8((int)v3.y, true);
    }
    a0 += shflx2(a0, 16); a1 += shflx2(a1, 16);    // merge 4 slots
    a2 += shflx2(a2, 16); a3 += shflx2(a3, 16);
    a0 += shflx2(a0, 32); a1 += shflx2(a1, 32);
    a2 += shflx2(a2, 32); a3 += shflx2(a3, 32);
    if (g == 0) {
        float h0 = fmaxf(a0[0] * iv + bflo(qv.x), 0.f);
        float h1 = fmaxf(a0[1] * iv + bfhi(qv.x), 0.f);
        float h2 = fmaxf(a1[0] * iv + bflo(qv.y), 0.f);
        float h3 = fmaxf(a1[1] * iv + bfhi(qv.y), 0.f);
        float h4 = fmaxf(a2[0] * iv + bflo(qv.z), 0.f);
        float h5 = fmaxf(a2[1] * iv + bfhi(qv.z), 0.f);
        float h6 = fmaxf(a3[0] * iv + bflo(qv.w), 0.f);
        float h7 = fmaxf(a3[1] * iv + bfhi(qv.w), 0.f);
        uint4 hw;
        hw.x = pk4bf(h0, h1); hw.y = pk4bf(h2, h3);
        hw.z = pk4bf(h4, h5); hw.w = pk4bf(h6, h7);
        *(uint4*)(hb + (long)n * 128 + lm * 8) = hw;
    }
}

// ---------- proj2 (standalone, 512 threads, 32KB static LDS for weights) -----------
__global__ void __launch_bounds__(512, 4)
proj2_kernel(const ushort* __restrict__ hb,
             const ushort* __restrict__ Wfl, const ushort* __restrict__ Wfr,
             const float* __restrict__ bias,
             unsigned char* __restrict__ u8, ushort* __restrict__ v, int N) {
    __shared__ ushort wsm[2 * 64 * 128];   // 32 KB
    proj_body<64, false>((int)blockIdx.x, (int)threadIdx.x, hb, Wfl, Wfr, bias, u8, v, N,
                         wsm);
}

// ---------- layer-2 aggregate + log_softmax ----------------------------------------
// One wave per node; 16 lanes/edge, 4B/lane, slot g owns 4 consecutive edges.
__global__ void __launch_bounds__(256)
agg_lsm_kernel(const unsigned char* __restrict__ u8,   // (N+1) x 64 fp8, row N = 0
               const ushort* __restrict__ v,           // (N+1) x 64 bf16
               const int* __restrict__ ssrc,
               const int* __restrict__ rsd,            // [2N] {row_start, padded_deg}
               const float* __restrict__ inv_deg,
               float* __restrict__ out, int N) {
    int wave = threadIdx.x >> 6, lane = threadIdx.x & 63;
    int n = blockIdx.x * 4 + wave;
    if (n >= N) return;
    int g = lane >> 4, lm = lane & 15;             // 4 edge slots / cols lm*4..lm*4+3
    int2 rv = *(const int2*)(rsd + 2 * n);
    int start = rv.x, dp = rv.y;
    float iv = inv_deg[n];                         // hoisted
    uint2 vv2 = *(const uint2*)(v + (long)n * 64 + lm * 4);   // hoisted
    const int* sp = ssrc + start;
    const unsigned char* ub = u8 + lm * 4;
    f32x2 a0 = (f32x2)0.f, a1 = (f32x2)0.f;
    int4 s = *(const int4*)(sp + 4 * g);           // slot g: edges 4g..4g+3
    for (int j = 0; j < dp; j += 16) {
        unsigned v0 = *(const unsigned*)(ub + (unsigned)s.x * 64u);
        unsigned v1 = *(const unsigned*)(ub + (unsigned)s.y * 64u);
        unsigned v2 = *(const unsigned*)(ub + (unsigned)s.z * 64u);
        unsigned v3 = *(const unsigned*)(ub + (unsigned)s.w * 64u);
        s = *(const int4*)(sp + j + 16 + 4 * g);   // prefetch next batch (tail-safe)
        a0 += __builtin_amdgcn_cvt_pk_f32_fp8((int)v0, false);
        a1 += __builtin_amdgcn_cvt_pk_f32_fp8((int)v0, true);
        a0 += __builtin_amdgcn_cvt_pk_f32_fp8((int)v1, false);
        a1 += __builtin_amdgcn_cvt_pk_f32_fp8((int)v1, true);
        a0 += __builtin_amdgcn_cvt_pk_f32_fp8((int)v2, false);
        a1 += __builtin_amdgcn_cvt_pk_f32_fp8((int)v2, true);
        a0 += __builtin_amdgcn_cvt_pk_f32_fp8((int)v3, false);
        a1 += __builtin_amdgcn_cvt_pk_f32_fp8((int)v3, true);
    }
    a0 += shflx2(a0, 16); a1 += shflx2(a1, 16);    // merge 4 slots
    a0 += shflx2(a0, 32); a1 += shflx2(a1, 32);

    float z0 = a0[0] * iv + bflo(vv2.x), z1 = a0[1] * iv + bfhi(vv2.x);
    float z2 = a1[0] * iv + bflo(vv2.y), z3 = a1[1] * iv + bfhi(vv2.y);
    float mx = fmaxf(fmaxf(z0, z1), fmaxf(z2, z3));
#pragma unroll
    for (int o = 8; o > 0; o >>= 1) mx = fmaxf(mx, __shfl_xor(mx, o));   // over lm bits
    float e = (__expf(z0 - mx) + __expf(z1 - mx)) + (__expf(z2 - mx) + __expf(z3 - mx));
#pragma unroll
    for (int o = 8; o > 0; o >>= 1) e += __shfl_xor(e, o);
    float ls = mx + __logf(e);
    if (g == 0) {                                  // 16 lanes store 4 floats each
        float4 o0;
        o0.x = z0 - ls; o0.y = z1 - ls; o0.z = z2 - ls; o0.w = z3 - ls;
        *(float4*)(out + (long)n * 64 + lm * 4) = o0;
    }
}

// -----------------------------------------------------------------------------------
extern "C" void kernel_launch(void* const* d_in, const int* in_sizes, int n_in,
                              void* d_out, int out_size, void* d_ws, size_t ws_size,
                              hipStream_t stream) {
    const float* x   = (const float*)d_in[0];
    const int*   ei  = (const int*)d_in[1];
    const float* Wl1 = (const float*)d_in[2];
    const float* Wr1 = (const float*)d_in[3];
    const float* b1  = (const float*)d_in[4];
    const float* Wl2 = (const float*)d_in[5];
    const float* Wr2 = (const float*)d_in[6];
    const float* b2  = (const float*)d_in[7];

    const int N = in_sizes[0] / 128;
    const int E = in_sizes[1] / 2;
    const int* src = ei;
    const int* dst = ei + E;
    const int NB = (N + NPB - 1) / NPB;             // 196 buckets for N=100000
    const int NSC = (E + CHUNK - 1) / CHUNK;        // 196 scatter blocks

    size_t off = 0;
    auto take = [&](size_t nbytes) -> void* {
        void* ptr = (void*)((char*)d_ws + off);
        off += (nbytes + 255) & ~(size_t)255;
        return ptr;
    };
    int*      bcount    = (int*)take((size_t)NB * 4);
    unsigned* bbuf      = (unsigned*)take((size_t)NB * BCAP * 4);   // 12.8 MB
    int*      rsd       = (int*)take((size_t)N * 8);                // {row_start, pdeg}
    float*    inv_deg   = (float*)take((size_t)N * 4);
    int*      ssrc      = (int*)take((size_t)NB * BCAP * 4);        // 12.8 MB (bucket-strided)
    unsigned char* p8   = (unsigned char*)take((size_t)(N + 1) * 128);    // +sentinel row
    ushort*   q         = (ushort*)take((size_t)(N + 1) * 128 * 2);       // +sentinel row
    ushort*   hb        = (ushort*)take((size_t)N * 128 * 2);
    ushort*   Wf_l1     = (ushort*)take(128 * 128 * 2);
    ushort*   Wf_r1     = (ushort*)take(128 * 128 * 2);
    ushort*   Wf_l2     = (ushort*)take(64 * 128 * 2);
    ushort*   Wf_r2     = (ushort*)take(64 * 128 * 2);
    unsigned char* u8 = p8;   // p dead after agg_relu; u8 row N rewritten 0 by proj2
    ushort*        v  = q;    // q dead after agg_relu
    (void)ws_size; (void)n_in; (void)out_size;

    static bool attr_set = false;                   // allow 64KB dynamic LDS for k2
    if (!attr_set) {
        hipFuncSetAttribute((const void*)k2_csr_proj1,
                            hipFuncAttributeMaxDynamicSharedMemorySize, 65536);
        attr_set = true;
    }

    hipMemsetAsync(bcount, 0, (size_t)NB * 4, stream);

    // K1: scatter || weight repack (independent)
    k1_scatter_cvtw<<<NSC + 192, 256, 0, stream>>>(src, dst, bcount, bbuf, E, NSC,
                                                   Wl1, Wr1, Wl2, Wr2,
                                                   Wf_l1, Wf_r1, Wf_l2, Wf_r2);

    // K2: build_csr (padded lists, shuffle-scan) || proj1 (LDS-staged weights)
    int P1 = (N + 127) / 128;
    k2_csr_proj1<<<NB + P1, 512, 65536, stream>>>(bbuf, bcount, rsd, inv_deg,
                                                  ssrc, NB, N, x, Wf_l1, Wf_r1, b1, p8, q);

    // layer 1 aggregate
    agg_relu_kernel<<<(N + 3) / 4, 256, 0, stream>>>(p8, q, ssrc, rsd, inv_deg, hb, N);

    // layer 2
    proj2_kernel<<<(N + 127) / 128, 512, 0, stream>>>(hb, Wf_l2, Wf_r2, b2, u8, v, N);
    agg_lsm_kernel<<<(N + 3) / 4, 256, 0, stream>>>(u8, v, ssrc, rsd, inv_deg,
                                                    (float*)d_out, N);
}

// Round 5
// 242.405 us; speedup vs baseline: 1.1768x; 1.0020x over previous
//
#include <hip/hip_runtime.h>
#include <hip/hip_bf16.h>

// GraphSAGE 2-layer, N=100K, E=1.6M, 128->128(relu)->64, log_softmax. fp32 in/out.
//
//   p = fp8(x@Wl1); q = bf16(x@Wr1 + b1)      (MFMA proj, operand-swapped, LDS-staged W)
//   h = bf16(relu(mean_nbr(p) + q))            (gather: 2 nodes/wave, padded lists)
//   u = fp8(h@Wl2); v = bf16(h@Wr2 + b2)       (MFMA proj, LDS-staged W)
//   out = log_softmax(mean_nbr(u) + v)         (gather: 2 nodes/wave, padded lists)
//
// r13: everything latency-bound (k2: Mfma 4.9/VALU 6.3/occ 30; aggs similar).
//  - aggs: TWO nodes per wave = two independent idx->gather chains (2x MLP/wave).
//    Common min(dpA,dpB) rounds dual-issue; rare single-node continuation loops.
//    Padded lists + sentinel tails make all prefetch overruns safe, no predication.
//  - k2 CSR: bucket entries cached in LDS during histogram; scatter reads LDS
//    (removes 4 serial global rounds/thread). CSR blocks had 60KB LDS spare.
//  - proj1 untouched on purpose: if k2 doesn't move, pole = proj x-load latency.

typedef __attribute__((ext_vector_type(8))) short short8;   // 8 x bf16 = 4 VGPRs
typedef __attribute__((ext_vector_type(4))) float f32x4;
typedef __attribute__((ext_vector_type(2))) float f32x2;

#define NPB 512          // nodes per bucket (dst >> 9)
#define BCAP 16384       // edge capacity per bucket (padded mean ~11.8K)
#define CHUNK 8192       // edges per bucket_scatter block

__device__ __forceinline__ ushort f2bf(float f) {           // round-to-nearest-even
    unsigned u = __float_as_uint(f);
    return (ushort)((u + 0x7fff + ((u >> 16) & 1)) >> 16);
}
__device__ __forceinline__ float bflo(unsigned v) { return __uint_as_float(v << 16); }
__device__ __forceinline__ float bfhi(unsigned v) { return __uint_as_float(v & 0xffff0000u); }
__device__ __forceinline__ unsigned pk4bf(float a, float b) {   // 1 VOP3 (RNE)
    unsigned r;
    asm("v_cvt_pk_bf16_f32 %0, %1, %2" : "=v"(r) : "v"(a), "v"(b));
    return r;
}
__device__ __forceinline__ f32x2 shflx2(f32x2 v, int m) {
    f32x2 r; r[0] = __shfl_xor(v[0], m); r[1] = __shfl_xor(v[1], m); return r;
}

// ---------- weight repack into MFMA fragment order ---------------------------------
// Wf idx = ((ct*16 + kc)*16 + m)*8 + j holds W[k=kc*8+j][c=ct*16+m]
__device__ __forceinline__ void wfrag_one(const float* W, ushort* Wf, int i, int COLS) {
    int j = i & 7, m = (i >> 3) & 15, kc = (i >> 7) & 15, ct = i >> 11;
    Wf[i] = f2bf(W[(kc * 8 + j) * COLS + ct * 16 + m]);
}

// ---------- K1: bucket_scatter (blocks 0..NSC) || cvt_w (rest) ---------------------
__global__ void __launch_bounds__(256)
k1_scatter_cvtw(const int* __restrict__ src, const int* __restrict__ dst,
                int* __restrict__ bcount, unsigned* __restrict__ bbuf, int E, int NSC,
                const float* __restrict__ Wl1, const float* __restrict__ Wr1,
                const float* __restrict__ Wl2, const float* __restrict__ Wr2,
                ushort* __restrict__ Wf_l1, ushort* __restrict__ Wf_r1,
                ushort* __restrict__ Wf_l2, ushort* __restrict__ Wf_r2) {
    int tid = threadIdx.x;
    if ((int)blockIdx.x >= NSC) {
        int i = ((int)blockIdx.x - NSC) * 256 + tid;   // 49152 total
        if (i < 16384)       wfrag_one(Wl1, Wf_l1, i, 128);
        else if (i < 32768)  wfrag_one(Wr1, Wf_r1, i - 16384, 128);
        else if (i < 40960)  wfrag_one(Wl2, Wf_l2, i - 32768, 64);
        else if (i < 49152)  wfrag_one(Wr2, Wf_r2, i - 40960, 64);
        return;
    }
    __shared__ unsigned entry[CHUNK];        // 32 KB: (src<<9)|(dst&511)
    __shared__ unsigned char ebkt[CHUNK];    // 8 KB: bucket id (dst>>9 < 256)
    __shared__ int lhist[256], lbase[256], lcur[256];
    lhist[tid] = 0;
    __syncthreads();
    int e0 = blockIdx.x * CHUNK;
    int cnt = min(CHUNK, E - e0);
    int nv = cnt >> 2;
    for (int t = tid; t < nv; t += 256) {
        int4 d4 = ((const int4*)(dst + e0))[t];
        int4 s4 = ((const int4*)(src + e0))[t];
        int i = t * 4;
        int b0 = d4.x >> 9, b1 = d4.y >> 9, b2 = d4.z >> 9, b3 = d4.w >> 9;
        entry[i + 0] = ((unsigned)s4.x << 9) | (unsigned)(d4.x & 511);
        entry[i + 1] = ((unsigned)s4.y << 9) | (unsigned)(d4.y & 511);
        entry[i + 2] = ((unsigned)s4.z << 9) | (unsigned)(d4.z & 511);
        entry[i + 3] = ((unsigned)s4.w << 9) | (unsigned)(d4.w & 511);
        ebkt[i + 0] = (unsigned char)b0; ebkt[i + 1] = (unsigned char)b1;
        ebkt[i + 2] = (unsigned char)b2; ebkt[i + 3] = (unsigned char)b3;
        atomicAdd(&lhist[b0], 1); atomicAdd(&lhist[b1], 1);
        atomicAdd(&lhist[b2], 1); atomicAdd(&lhist[b3], 1);
    }
    for (int i = (nv << 2) + tid; i < cnt; i += 256) {
        int d = dst[e0 + i], s = src[e0 + i];
        int b = d >> 9;
        entry[i] = ((unsigned)s << 9) | (unsigned)(d & 511);
        ebkt[i] = (unsigned char)b;
        atomicAdd(&lhist[b], 1);
    }
    __syncthreads();
    int h = lhist[tid];
    lbase[tid] = (h > 0) ? atomicAdd(&bcount[tid], h) : 0;
    lcur[tid] = 0;
    __syncthreads();
    for (int i = tid; i < cnt; i += 256) {
        int b = ebkt[i];
        int o = atomicAdd(&lcur[b], 1);
        bbuf[(long)b * BCAP + lbase[b] + o] = entry[i];
    }
}

// ---------- stage both weight fragment arrays into LDS (linear copy) ---------------
template <int CTOT>
__device__ __forceinline__ void stage_weights(const ushort* __restrict__ Wfl,
                                              const ushort* __restrict__ Wfr,
                                              ushort* dst, int tid) {
    constexpr int HALF = CTOT / 2;            // ushorts per matrix
    constexpr int ITERS = (CTOT * 2) / 8192;  // 512 thr * 16B per iter
#pragma unroll
    for (int r = 0; r < ITERS; ++r) {
        int u = r * 4096 + tid * 8;           // ushort index; half uniform per r
        const ushort* s = (u < HALF) ? (Wfl + u) : (Wfr + (u - HALF));
        *(short8*)(dst + u) = *(const short8*)s;
    }
}

// ---------- dual projection body: p = fp8(X@Wl), q = bf16(X@Wr + b) ----------------
// Operand-swapped MFMA: D = Wfrag(A) * Xfrag(B) => lane holds 4 consecutive output
// cols of one node per ct. 512 threads, 8 waves x 16 rows; weights in LDS.
// Writes rows 0..N: row N is the ZERO sentinel row consumed by padded gathers.
template <int COLS, bool F32IN>
__device__ __forceinline__ void proj_body(int bid, int tid,
                            const void* __restrict__ xin,
                            const ushort* __restrict__ Wfl, const ushort* __restrict__ Wfr,
                            const float* __restrict__ bias,
                            unsigned char* __restrict__ p8, ushort* __restrict__ q, int N,
                            ushort* wsm) {
    constexpr int CT = COLS / 16;
    stage_weights<2 * COLS * 128>(Wfl, Wfr, wsm, tid);
    __syncthreads();
    const ushort* Wl = wsm;                  // LDS, linear = global Wf layout
    const ushort* Wr = wsm + COLS * 128;

    int wave = tid >> 6, lane = tid & 63;
    int quad = lane >> 4, m = lane & 15;
    long row0 = (long)bid * 128 + wave * 16;
    long node = row0 + m;
    long arow = (node < N) ? node : (N - 1);

    f32x4 accp[CT], accq[CT];
#pragma unroll
    for (int ct = 0; ct < CT; ++ct) { accp[ct] = (f32x4)0.0f; accq[ct] = (f32x4)0.0f; }

#pragma unroll
    for (int kk = 0; kk < 128; kk += 32) {
        short8 b;                            // B-frag: B[k][n=lane&15] = x[node][k]
        if (F32IN) {
            const float* xf = (const float*)xin + arow * 128 + kk + quad * 8;
            float4 f0 = *(const float4*)xf;
            float4 f1 = *(const float4*)(xf + 4);
            union { short8 s; unsigned u[4]; } bu;
            bu.u[0] = pk4bf(f0.x, f0.y);
            bu.u[1] = pk4bf(f0.z, f0.w);
            bu.u[2] = pk4bf(f1.x, f1.y);
            bu.u[3] = pk4bf(f1.z, f1.w);
            b = bu.s;
        } else {
            b = *(const short8*)((const ushort*)xin + arow * 128 + kk + quad * 8);
        }
        int kc = (kk >> 3) + quad;
#pragma unroll
        for (int ct = 0; ct < CT; ++ct) {
            int boff = ((ct * 16 + kc) * 16 + m) * 8;      // 32-bit LDS addressing
            short8 al = *(const short8*)(Wl + boff);       // ds_read_b128
            short8 ar = *(const short8*)(Wr + boff);
            accp[ct] = __builtin_amdgcn_mfma_f32_16x16x32_bf16(al, b, accp[ct], 0, 0, 0);
            accq[ct] = __builtin_amdgcn_mfma_f32_16x16x32_bf16(ar, b, accq[ct], 0, 0, 0);
        }
    }

    if (node <= N) {                          // row N = zero sentinel
        unsigned msk = (node == N) ? 0u : ~0u;
#pragma unroll
        for (int ct = 0; ct < CT; ++ct) {
            int c0 = ct * 16 + quad * 4;
            float4 bv = *(const float4*)(bias + c0);
            float q0 = accq[ct][0] + bv.x, q1 = accq[ct][1] + bv.y;
            float q2 = accq[ct][2] + bv.z, q3 = accq[ct][3] + bv.w;
            unsigned w = (unsigned)__builtin_amdgcn_cvt_pk_fp8_f32(accp[ct][0], accp[ct][1], 0, false);
            w = (unsigned)__builtin_amdgcn_cvt_pk_fp8_f32(accp[ct][2], accp[ct][3], (int)w, true);
            *(unsigned*)(p8 + node * COLS + c0) = w & msk;
            uint2 qw; qw.x = pk4bf(q0, q1) & msk; qw.y = pk4bf(q2, q3) & msk;
            *(uint2*)(q + node * COLS + c0) = qw;
        }
    }
}

// ---------- K2: build_csr (blocks 0..NB) || proj1 ----------------------------------
// 512 threads. Dynamic LDS (64KB): proj blocks stage weights; CSR blocks cache the
// bucket's entries in LDS (histogram pass) so the scatter pass never re-reads global.
__global__ void __launch_bounds__(512, 4)
k2_csr_proj1(const unsigned* __restrict__ bbuf, const int* __restrict__ bcount,
             int* __restrict__ rsd,            // [2N]: {row_start, padded_deg}
             float* __restrict__ inv_deg, int* __restrict__ ssrc, int NBcsr, int N,
             const float* __restrict__ x,
             const ushort* __restrict__ Wfl, const ushort* __restrict__ Wfr,
             const float* __restrict__ bias,
             unsigned char* __restrict__ p8, ushort* __restrict__ q) {
    extern __shared__ char smem[];
    int tid = threadIdx.x;
    if ((int)blockIdx.x >= NBcsr) {
        proj_body<128, true>((int)blockIdx.x - NBcsr, tid, x, Wfl, Wfr, bias, p8, q, N,
                             (ushort*)smem);
        return;
    }
    int* sdeg = (int*)smem;           // [512]
    int* lcur = sdeg + NPB;           // [512]
    int* wsum = lcur + NPB;           // [16] (padded to keep ecache 16B-aligned)
    unsigned* ecache = (unsigned*)(wsum + 16);   // 15344 entries (57KB)
    const int ECAPV = 3836;           // uint4 slots in ecache
    int b = blockIdx.x;
    int node0 = b * NPB;
    sdeg[tid] = 0;
    __syncthreads();
    int cnt = bcount[b];
    long base = (long)b * BCAP;
    const unsigned* bb = bbuf + base;
    int nv = cnt >> 2;
    int cnv = min(nv, ECAPV);
    for (int t = tid; t < nv; t += 512) {          // histogram + LDS entry cache
        uint4 e = ((const uint4*)bb)[t];
        if (t < cnv) ((uint4*)ecache)[t] = e;
        atomicAdd(&sdeg[e.x & 511], 1);
        atomicAdd(&sdeg[e.y & 511], 1);
        atomicAdd(&sdeg[e.z & 511], 1);
        atomicAdd(&sdeg[e.w & 511], 1);
    }
    for (int i = (nv << 2) + tid; i < cnt; i += 512)
        atomicAdd(&sdeg[bb[i] & 511], 1);
    __syncthreads();
    int lane = tid & 63, wv = tid >> 6;
    int c0 = sdeg[tid];
    int dp = (c0 + 15) & ~15;                       // padded degree
    int v = dp;                                     // wave-shuffle inclusive scan of dp
#pragma unroll
    for (int o = 1; o < 64; o <<= 1) {
        int t = __shfl_up(v, o);
        if (lane >= o) v += t;
    }
    if (lane == 63) wsum[wv] = v;
    __syncthreads();
    int add = 0;
    for (int w = 0; w < wv; ++w) add += wsum[w];
    int rs0 = v + add - dp;                         // bucket-local exclusive prefix
    lcur[tid] = rs0;
    if (node0 + tid < N) {
        int2 rv; rv.x = (int)(base + rs0); rv.y = dp;
        *(int2*)(rsd + 2 * (node0 + tid)) = rv;
        inv_deg[node0 + tid] = 1.0f / (float)(c0 > 1 ? c0 : 1);
    }
    __syncthreads();
    for (int t = tid; t < cnv; t += 512) {         // scatter from LDS cache
        uint4 e = ((const uint4*)ecache)[t];
        int p0 = atomicAdd(&lcur[e.x & 511], 1);
        int p1 = atomicAdd(&lcur[e.y & 511], 1);
        int p2 = atomicAdd(&lcur[e.z & 511], 1);
        int p3 = atomicAdd(&lcur[e.w & 511], 1);
        ssrc[base + p0] = (int)(e.x >> 9);
        ssrc[base + p1] = (int)(e.y >> 9);
        ssrc[base + p2] = (int)(e.z >> 9);
        ssrc[base + p3] = (int)(e.w >> 9);
    }
    for (int t = cnv + tid; t < nv; t += 512) {    // overflow (never in practice)
        uint4 e = ((const uint4*)bb)[t];
        int p0 = atomicAdd(&lcur[e.x & 511], 1);
        int p1 = atomicAdd(&lcur[e.y & 511], 1);
        int p2 = atomicAdd(&lcur[e.z & 511], 1);
        int p3 = atomicAdd(&lcur[e.w & 511], 1);
        ssrc[base + p0] = (int)(e.x >> 9);
        ssrc[base + p1] = (int)(e.y >> 9);
        ssrc[base + p2] = (int)(e.z >> 9);
        ssrc[base + p3] = (int)(e.w >> 9);
    }
    for (int i = (nv << 2) + tid; i < cnt; i += 512) {
        unsigned w = bb[i];
        int pos = atomicAdd(&lcur[w & 511], 1);
        ssrc[base + pos] = (int)(w >> 9);
    }
    // padding fill (disjoint from scatter ranges -> no barrier needed)
    for (int i = c0; i < dp; ++i) ssrc[base + rs0 + i] = N;
    if (tid == 511) {                               // bucket tail for prefetch overrun
        int tot = v + add;
        for (int k = 0; k < 16; ++k) ssrc[base + tot + k] = N;
    }
}

// ---------- layer-1 aggregate: h = bf16(relu(mean_nbr(p) + q)) ---------------------
// TWO nodes per wave (independent gather chains = 2x MLP). 16 lanes/edge, 8B/lane,
// slot g owns 4 consecutive edges. Padded lists: no predication, safe prefetch.
__global__ void __launch_bounds__(256)
agg_relu_kernel(const unsigned char* __restrict__ p8,  // (N+1) x 128 fp8, row N = 0
                const ushort* __restrict__ q,          // (N+1) x 128 bf16
                const int* __restrict__ ssrc,
                const int* __restrict__ rsd,           // [2N] {row_start, padded_deg}
                const float* __restrict__ inv_deg,
                ushort* __restrict__ hb, int N) {
    int wave = threadIdx.x >> 6, lane = threadIdx.x & 63;
    int nA = blockIdx.x * 8 + wave * 2;
    if (nA >= N) return;
    int nB = nA + 1;
    bool hasB = (nB < N);
    int g = lane >> 4, lm = lane & 15;             // 4 edge slots / cols lm*8..lm*8+7
    int2 rvA = *(const int2*)(rsd + 2 * nA);
    int2 rvB = hasB ? *(const int2*)(rsd + 2 * nB) : make_int2(rvA.x, 0);
    int dpA = rvA.y, dpB = rvB.y;
    float ivA = inv_deg[nA];
    float ivB = hasB ? inv_deg[nB] : 0.f;
    uint4 qvA = make_uint4(0u,0u,0u,0u), qvB = make_uint4(0u,0u,0u,0u);
    if (g == 0) {
        qvA = *(const uint4*)(q + (long)nA * 128 + lm * 8);
        if (hasB) qvB = *(const uint4*)(q + (long)nB * 128 + lm * 8);
    }
    const int* spA = ssrc + rvA.x;
    const int* spB = ssrc + rvB.x;
    const unsigned char* pb = p8 + lm * 8;
    f32x2 aA0=(f32x2)0.f, aA1=(f32x2)0.f, aA2=(f32x2)0.f, aA3=(f32x2)0.f;
    f32x2 aB0=(f32x2)0.f, aB1=(f32x2)0.f, aB2=(f32x2)0.f, aB3=(f32x2)0.f;
    int4 sA = *(const int4*)(spA + 4 * g);
    int4 sB = *(const int4*)(spB + 4 * g);
    int dmin = min(dpA, dpB);
    int j = 0;
    for (; j < dmin; j += 16) {                    // dual-issue: 8 gathers in flight
        uint2 a0 = *(const uint2*)(pb + (unsigned)sA.x * 128u);
        uint2 a1 = *(const uint2*)(pb + (unsigned)sA.y * 128u);
        uint2 a2 = *(const uint2*)(pb + (unsigned)sA.z * 128u);
        uint2 a3 = *(const uint2*)(pb + (unsigned)sA.w * 128u);
        uint2 b0 = *(const uint2*)(pb + (unsigned)sB.x * 128u);
        uint2 b1 = *(const uint2*)(pb + (unsigned)sB.y * 128u);
        uint2 b2 = *(const uint2*)(pb + (unsigned)sB.z * 128u);
        uint2 b3 = *(const uint2*)(pb + (unsigned)sB.w * 128u);
        sA = *(const int4*)(spA + j + 16 + 4 * g);
        sB = *(const int4*)(spB + j + 16 + 4 * g);
        aA0 += __builtin_amdgcn_cvt_pk_f32_fp8((int)a0.x, false);
        aA1 += __builtin_amdgcn_cvt_pk_f32_fp8((int)a0.x, true);
        aA2 += __builtin_amdgcn_cvt_pk_f32_fp8((int)a0.y, false);
        aA3 += __builtin_amdgcn_cvt_pk_f32_fp8((int)a0.y, true);
        aA0 += __builtin_amdgcn_cvt_pk_f32_fp8((int)a1.x, false);
        aA1 += __builtin_amdgcn_cvt_pk_f32_fp8((int)a1.x, true);
        aA2 += __builtin_amdgcn_cvt_pk_f32_fp8((int)a1.y, false);
        aA3 += __builtin_amdgcn_cvt_pk_f32_fp8((int)a1.y, true);
        aA0 += __builtin_amdgcn_cvt_pk_f32_fp8((int)a2.x, false);
        aA1 += __builtin_amdgcn_cvt_pk_f32_fp8((int)a2.x, true);
        aA2 += __builtin_amdgcn_cvt_pk_f32_fp8((int)a2.y, false);
        aA3 += __builtin_amdgcn_cvt_pk_f32_fp8((int)a2.y, true);
        aA0 += __builtin_amdgcn_cvt_pk_f32_fp8((int)a3.x, false);
        aA1 += __builtin_amdgcn_cvt_pk_f32_fp8((int)a3.x, true);
        aA2 += __builtin_amdgcn_cvt_pk_f32_fp8((int)a3.y, false);
        aA3 += __builtin_amdgcn_cvt_pk_f32_fp8((int)a3.y, true);
        aB0 += __builtin_amdgcn_cvt_pk_f32_fp8((int)b0.x, false);
        aB1 += __builtin_amdgcn_cvt_pk_f32_fp8((int)b0.x, true);
        aB2 += __builtin_amdgcn_cvt_pk_f32_fp8((int)b0.y, false);
        aB3 += __builtin_amdgcn_cvt_pk_f32_fp8((int)b0.y, true);
        aB0 += __builtin_amdgcn_cvt_pk_f32_fp8((int)b1.x, false);
        aB1 += __builtin_amdgcn_cvt_pk_f32_fp8((int)b1.x, true);
        aB2 += __builtin_amdgcn_cvt_pk_f32_fp8((int)b1.y, false);
        aB3 += __builtin_amdgcn_cvt_pk_f32_fp8((int)b1.y, true);
        aB0 += __builtin_amdgcn_cvt_pk_f32_fp8((int)b2.x, false);
        aB1 += __builtin_amdgcn_cvt_pk_f32_fp8((int)b2.x, true);
        aB2 += __builtin_amdgcn_cvt_pk_f32_fp8((int)b2.y, false);
        aB3 += __builtin_amdgcn_cvt_pk_f32_fp8((int)b2.y, true);
        aB0 += __builtin_amdgcn_cvt_pk_f32_fp8((int)b3.x, false);
        aB1 += __builtin_amdgcn_cvt_pk_f32_fp8((int)b3.x, true);
        aB2 += __builtin_amdgcn_cvt_pk_f32_fp8((int)b3.y, false);
        aB3 += __builtin_amdgcn_cvt_pk_f32_fp8((int)b3.y, true);
    }
    for (; j < dpA; j += 16) {                     // A continuation (rare)
        uint2 a0 = *(const uint2*)(pb + (unsigned)sA.x * 128u);
        uint2 a1 = *(const uint2*)(pb + (unsigned)sA.y * 128u);
        uint2 a2 = *(const uint2*)(pb + (unsigned)sA.z * 128u);
        uint2 a3 = *(const uint2*)(pb + (unsigned)sA.w * 128u);
        sA = *(const int4*)(spA + j + 16 + 4 * g);
        aA0 += __builtin_amdgcn_cvt_pk_f32_fp8((int)a0.x, false);
        aA1 += __builtin_amdgcn_cvt_pk_f32_fp8((int)a0.x, true);
        aA2 += __builtin_amdgcn_cvt_pk_f32_fp8((int)a0.y, false);
        aA3 += __builtin_amdgcn_cvt_pk_f32_fp8((int)a0.y, true);
        aA0 += __builtin_amdgcn_cvt_pk_f32_fp8((int)a1.x, false);
        aA1 += __builtin_amdgcn_cvt_pk_f32_fp8((int)a1.x, true);
        aA2 += __builtin_amdgcn_cvt_pk_f32_fp8((int)a1.y, false);
        aA3 += __builtin_amdgcn_cvt_pk_f32_fp8((int)a1.y, true);
        aA0 += __builtin_amdgcn_cvt_pk_f32_fp8((int)a2.x, false);
        aA1 += __builtin_amdgcn_cvt_pk_f32_fp8((int)a2.x, true);
        aA2 += __builtin_amdgcn_cvt_pk_f32_fp8((int)a2.y, false);
        aA3 += __builtin_amdgcn_cvt_pk_f32_fp8((int)a2.y, true);
        aA0 += __builtin_amdgcn_cvt_pk_f32_fp8((int)a3.x, false);
        aA1 += __builtin_amdgcn_cvt_pk_f32_fp8((int)a3.x, true);
        aA2 += __builtin_amdgcn_cvt_pk_f32_fp8((int)a3.y, false);
        aA3 += __builtin_amdgcn_cvt_pk_f32_fp8((int)a3.y, true);
    }
    for (; j < dpB; j += 16) {                     // B continuation (rare)
        uint2 b0 = *(const uint2*)(pb + (unsigned)sB.x * 128u);
        uint2 b1 = *(const uint2*)(pb + (unsigned)sB.y * 128u);
        uint2 b2 = *(const uint2*)(pb + (unsigned)sB.z * 128u);
        uint2 b3 = *(const uint2*)(pb + (unsigned)sB.w * 128u);
        sB = *(const int4*)(spB + j + 16 + 4 * g);
        aB0 += __builtin_amdgcn_cvt_pk_f32_fp8((int)b0.x, false);
        aB1 += __builtin_amdgcn_cvt_pk_f32_fp8((int)b0.x, true);
        aB2 += __builtin_amdgcn_cvt_pk_f32_fp8((int)b0.y, false);
        aB3 += __builtin_amdgcn_cvt_pk_f32_fp8((int)b0.y, true);
        aB0 += __builtin_amdgcn_cvt_pk_f32_fp8((int)b1.x, false);
        aB1 += __builtin_amdgcn_cvt_pk_f32_fp8((int)b1.x, true);
        aB2 += __builtin_amdgcn_cvt_pk_f32_fp8((int)b1.y, false);
        aB3 += __builtin_amdgcn_cvt_pk_f32_fp8((int)b1.y, true);
        aB0 += __builtin_amdgcn_cvt_pk_f32_fp8((int)b2.x, false);
        aB1 += __builtin_amdgcn_cvt_pk_f32_fp8((int)b2.x, true);
        aB2 += __builtin_amdgcn_cvt_pk_f32_fp8((int)b2.y, false);
        aB3 += __builtin_amdgcn_cvt_pk_f32_fp8((int)b2.y, true);
        aB0 += __builtin_amdgcn_cvt_pk_f32_fp8((int)b3.x, false);
        aB1 += __builtin_amdgcn_cvt_pk_f32_fp8((int)b3.x, true);
        aB2 += __builtin_amdgcn_cvt_pk_f32_fp8((int)b3.y, false);
        aB3 += __builtin_amdgcn_cvt_pk_f32_fp8((int)b3.y, true);
    }
    aA0 += shflx2(aA0, 16); aA1 += shflx2(aA1, 16);
    aA2 += shflx2(aA2, 16); aA3 += shflx2(aA3, 16);
    aB0 += shflx2(aB0, 16); aB1 += shflx2(aB1, 16);
    aB2 += shflx2(aB2, 16); aB3 += shflx2(aB3, 16);
    aA0 += shflx2(aA0, 32); aA1 += shflx2(aA1, 32);
    aA2 += shflx2(aA2, 32); aA3 += shflx2(aA3, 32);
    aB0 += shflx2(aB0, 32); aB1 += shflx2(aB1, 32);
    aB2 += shflx2(aB2, 32); aB3 += shflx2(aB3, 32);
    if (g == 0) {
        float h0 = fmaxf(aA0[0] * ivA + bflo(qvA.x), 0.f);
        float h1 = fmaxf(aA0[1] * ivA + bfhi(qvA.x), 0.f);
        float h2 = fmaxf(aA1[0] * ivA + bflo(qvA.y), 0.f);
        float h3 = fmaxf(aA1[1] * ivA + bfhi(qvA.y), 0.f);
        float h4 = fmaxf(aA2[0] * ivA + bflo(qvA.z), 0.f);
        float h5 = fmaxf(aA2[1] * ivA + bfhi(qvA.z), 0.f);
        float h6 = fmaxf(aA3[0] * ivA + bflo(qvA.w), 0.f);
        float h7 = fmaxf(aA3[1] * ivA + bfhi(qvA.w), 0.f);
        uint4 hw;
        hw.x = pk4bf(h0, h1); hw.y = pk4bf(h2, h3);
        hw.z = pk4bf(h4, h5); hw.w = pk4bf(h6, h7);
        *(uint4*)(hb + (long)nA * 128 + lm * 8) = hw;
        if (hasB) {
            float g0 = fmaxf(aB0[0] * ivB + bflo(qvB.x), 0.f);
            float g1 = fmaxf(aB0[1] * ivB + bfhi(qvB.x), 0.f);
            float g2 = fmaxf(aB1[0] * ivB + bflo(qvB.y), 0.f);
            float g3 = fmaxf(aB1[1] * ivB + bfhi(qvB.y), 0.f);
            float g4 = fmaxf(aB2[0] * ivB + bflo(qvB.z), 0.f);
            float g5 = fmaxf(aB2[1] * ivB + bfhi(qvB.z), 0.f);
            float g6 = fmaxf(aB3[0] * ivB + bflo(qvB.w), 0.f);
            float g7 = fmaxf(aB3[1] * ivB + bfhi(qvB.w), 0.f);
            uint4 gw;
            gw.x = pk4bf(g0, g1); gw.y = pk4bf(g2, g3);
            gw.z = pk4bf(g4, g5); gw.w = pk4bf(g6, g7);
            *(uint4*)(hb + (long)nB * 128 + lm * 8) = gw;
        }
    }
}

// ---------- proj2 (standalone, 512 threads, 32KB static LDS for weights) -----------
__global__ void __launch_bounds__(512, 4)
proj2_kernel(const ushort* __restrict__ hb,
             const ushort* __restrict__ Wfl, const ushort* __restrict__ Wfr,
             const float* __restrict__ bias,
             unsigned char* __restrict__ u8, ushort* __restrict__ v, int N) {
    __shared__ ushort wsm[2 * 64 * 128];   // 32 KB
    proj_body<64, false>((int)blockIdx.x, (int)threadIdx.x, hb, Wfl, Wfr, bias, u8, v, N,
                         wsm);
}

// ---------- layer-2 aggregate + log_softmax ----------------------------------------
// TWO nodes per wave. 16 lanes/edge, 4B/lane, slot g owns 4 consecutive edges.
__global__ void __launch_bounds__(256)
agg_lsm_kernel(const unsigned char* __restrict__ u8,   // (N+1) x 64 fp8, row N = 0
               const ushort* __restrict__ v,           // (N+1) x 64 bf16
               const int* __restrict__ ssrc,
               const int* __restrict__ rsd,            // [2N] {row_start, padded_deg}
               const float* __restrict__ inv_deg,
               float* __restrict__ out, int N) {
    int wave = threadIdx.x >> 6, lane = threadIdx.x & 63;
    int nA = blockIdx.x * 8 + wave * 2;
    if (nA >= N) return;
    int nB = nA + 1;
    bool hasB = (nB < N);
    int g = lane >> 4, lm = lane & 15;             // 4 edge slots / cols lm*4..lm*4+3
    int2 rvA = *(const int2*)(rsd + 2 * nA);
    int2 rvB = hasB ? *(const int2*)(rsd + 2 * nB) : make_int2(rvA.x, 0);
    int dpA = rvA.y, dpB = rvB.y;
    float ivA = inv_deg[nA];
    float ivB = hasB ? inv_deg[nB] : 0.f;
    uint2 vvA = *(const uint2*)(v + (long)nA * 64 + lm * 4);
    uint2 vvB = hasB ? *(const uint2*)(v + (long)nB * 64 + lm * 4) : make_uint2(0u,0u);
    const int* spA = ssrc + rvA.x;
    const int* spB = ssrc + rvB.x;
    const unsigned char* ub = u8 + lm * 4;
    f32x2 aA0=(f32x2)0.f, aA1=(f32x2)0.f, aB0=(f32x2)0.f, aB1=(f32x2)0.f;
    int4 sA = *(const int4*)(spA + 4 * g);
    int4 sB = *(const int4*)(spB + 4 * g);
    int dmin = min(dpA, dpB);
    int j = 0;
    for (; j < dmin; j += 16) {                    // dual-issue: 8 gathers in flight
        unsigned a0 = *(const unsigned*)(ub + (unsigned)sA.x * 64u);
        unsigned a1 = *(const unsigned*)(ub + (unsigned)sA.y * 64u);
        unsigned a2 = *(const unsigned*)(ub + (unsigned)sA.z * 64u);
        unsigned a3 = *(const unsigned*)(ub + (unsigned)sA.w * 64u);
        unsigned b0 = *(const unsigned*)(ub + (unsigned)sB.x * 64u);
        unsigned b1 = *(const unsigned*)(ub + (unsigned)sB.y * 64u);
        unsigned b2 = *(const unsigned*)(ub + (unsigned)sB.z * 64u);
        unsigned b3 = *(const unsigned*)(ub + (unsigned)sB.w * 64u);
        sA = *(const int4*)(spA + j + 16 + 4 * g);
        sB = *(const int4*)(spB + j + 16 + 4 * g);
        aA0 += __builtin_amdgcn_cvt_pk_f32_fp8((int)a0, false);
        aA1 += __builtin_amdgcn_cvt_pk_f32_fp8((int)a0, true);
        aA0 += __builtin_amdgcn_cvt_pk_f32_fp8((int)a1, false);
        aA1 += __builtin_amdgcn_cvt_pk_f32_fp8((int)a1, true);
        aA0 += __builtin_amdgcn_cvt_pk_f32_fp8((int)a2, false);
        aA1 += __builtin_amdgcn_cvt_pk_f32_fp8((int)a2, true);
        aA0 += __builtin_amdgcn_cvt_pk_f32_fp8((int)a3, false);
        aA1 += __builtin_amdgcn_cvt_pk_f32_fp8((int)a3, true);
        aB0 += __builtin_amdgcn_cvt_pk_f32_fp8((int)b0, false);
        aB1 += __builtin_amdgcn_cvt_pk_f32_fp8((int)b0, true);
        aB0 += __builtin_amdgcn_cvt_pk_f32_fp8((int)b1, false);
        aB1 += __builtin_amdgcn_cvt_pk_f32_fp8((int)b1, true);
        aB0 += __builtin_amdgcn_cvt_pk_f32_fp8((int)b2, false);
        aB1 += __builtin_amdgcn_cvt_pk_f32_fp8((int)b2, true);
        aB0 += __builtin_amdgcn_cvt_pk_f32_fp8((int)b3, false);
        aB1 += __builtin_amdgcn_cvt_pk_f32_fp8((int)b3, true);
    }
    for (; j < dpA; j += 16) {                     // A continuation (rare)
        unsigned a0 = *(const unsigned*)(ub + (unsigned)sA.x * 64u);
        unsigned a1 = *(const unsigned*)(ub + (unsigned)sA.y * 64u);
        unsigned a2 = *(const unsigned*)(ub + (unsigned)sA.z * 64u);
        unsigned a3 = *(const unsigned*)(ub + (unsigned)sA.w * 64u);
        sA = *(const int4*)(spA + j + 16 + 4 * g);
        aA0 += __builtin_amdgcn_cvt_pk_f32_fp8((int)a0, false);
        aA1 += __builtin_amdgcn_cvt_pk_f32_fp8((int)a0, true);
        aA0 += __builtin_amdgcn_cvt_pk_f32_fp8((int)a1, false);
        aA1 += __builtin_amdgcn_cvt_pk_f32_fp8((int)a1, true);
        aA0 += __builtin_amdgcn_cvt_pk_f32_fp8((int)a2, false);
        aA1 += __builtin_amdgcn_cvt_pk_f32_fp8((int)a2, true);
        aA0 += __builtin_amdgcn_cvt_pk_f32_fp8((int)a3, false);
        aA1 += __builtin_amdgcn_cvt_pk_f32_fp8((int)a3, true);
    }
    for (; j < dpB; j += 16) {                     // B continuation (rare)
        unsigned b0 = *(const unsigned*)(ub + (unsigned)sB.x * 64u);
        unsigned b1 = *(const unsigned*)(ub + (unsigned)sB.y * 64u);
        unsigned b2 = *(const unsigned*)(ub + (unsigned)sB.z * 64u);
        unsigned b3 = *(const unsigned*)(ub + (unsigned)sB.w * 64u);
        sB = *(const int4*)(spB + j + 16 + 4 * g);
        aB0 += __builtin_amdgcn_cvt_pk_f32_fp8((int)b0, false);
        aB1 += __builtin_amdgcn_cvt_pk_f32_fp8((int)b0, true);
        aB0 += __builtin_amdgcn_cvt_pk_f32_fp8((int)b1, false);
        aB1 += __builtin_amdgcn_cvt_pk_f32_fp8((int)b1, true);
        aB0 += __builtin_amdgcn_cvt_pk_f32_fp8((int)b2, false);
        aB1 += __builtin_amdgcn_cvt_pk_f32_fp8((int)b2, true);
        aB0 += __builtin_amdgcn_cvt_pk_f32_fp8((int)b3, false);
        aB1 += __builtin_amdgcn_cvt_pk_f32_fp8((int)b3, true);
    }
    aA0 += shflx2(aA0, 16); aA1 += shflx2(aA1, 16);
    aB0 += shflx2(aB0, 16); aB1 += shflx2(aB1, 16);
    aA0 += shflx2(aA0, 32); aA1 += shflx2(aA1, 32);
    aB0 += shflx2(aB0, 32); aB1 += shflx2(aB1, 32);

    float zA0 = aA0[0] * ivA + bflo(vvA.x), zA1 = aA0[1] * ivA + bfhi(vvA.x);
    float zA2 = aA1[0] * ivA + bflo(vvA.y), zA3 = aA1[1] * ivA + bfhi(vvA.y);
    float zB0 = aB0[0] * ivB + bflo(vvB.x), zB1 = aB0[1] * ivB + bfhi(vvB.x);
    float zB2 = aB1[0] * ivB + bflo(vvB.y), zB3 = aB1[1] * ivB + bfhi(vvB.y);
    float mA = fmaxf(fmaxf(zA0, zA1), fmaxf(zA2, zA3));
    float mB = fmaxf(fmaxf(zB0, zB1), fmaxf(zB2, zB3));
#pragma unroll
    for (int o = 8; o > 0; o >>= 1) {              // over lm bits
        mA = fmaxf(mA, __shfl_xor(mA, o));
        mB = fmaxf(mB, __shfl_xor(mB, o));
    }
    float eA = (__expf(zA0 - mA) + __expf(zA1 - mA)) + (__expf(zA2 - mA) + __expf(zA3 - mA));
    float eB = (__expf(zB0 - mB) + __expf(zB1 - mB)) + (__expf(zB2 - mB) + __expf(zB3 - mB));
#pragma unroll
    for (int o = 8; o > 0; o >>= 1) {
        eA += __shfl_xor(eA, o);
        eB += __shfl_xor(eB, o);
    }
    float lsA = mA + __logf(eA);
    float lsB = mB + __logf(eB);
    if (g == 0) {                                  // 16 lanes store 4 floats each
        float4 oA;
        oA.x = zA0 - lsA; oA.y = zA1 - lsA; oA.z = zA2 - lsA; oA.w = zA3 - lsA;
        *(float4*)(out + (long)nA * 64 + lm * 4) = oA;
        if (hasB) {
            float4 oB;
            oB.x = zB0 - lsB; oB.y = zB1 - lsB; oB.z = zB2 - lsB; oB.w = zB3 - lsB;
            *(float4*)(out + (long)nB * 64 + lm * 4) = oB;
        }
    }
}

// -----------------------------------------------------------------------------------
extern "C" void kernel_launch(void* const* d_in, const int* in_sizes, int n_in,
                              void* d_out, int out_size, void* d_ws, size_t ws_size,
                              hipStream_t stream) {
    const float* x   = (const float*)d_in[0];
    const int*   ei  = (const int*)d_in[1];
    const float* Wl1 = (const float*)d_in[2];
    const float* Wr1 = (const float*)d_in[3];
    const float* b1  = (const float*)d_in[4];
    const float* Wl2 = (const float*)d_in[5];
    const float* Wr2 = (const float*)d_in[6];
    const float* b2  = (const float*)d_in[7];

    const int N = in_sizes[0] / 128;
    const int E = in_sizes[1] / 2;
    const int* src = ei;
    const int* dst = ei + E;
    const int NB = (N + NPB - 1) / NPB;             // 196 buckets for N=100000
    const int NSC = (E + CHUNK - 1) / CHUNK;        // 196 scatter blocks

    size_t off = 0;
    auto take = [&](size_t nbytes) -> void* {
        void* ptr = (void*)((char*)d_ws + off);
        off += (nbytes + 255) & ~(size_t)255;
        return ptr;
    };
    int*      bcount    = (int*)take((size_t)NB * 4);
    unsigned* bbuf      = (unsigned*)take((size_t)NB * BCAP * 4);   // 12.8 MB
    int*      rsd       = (int*)take((size_t)N * 8);                // {row_start, pdeg}
    float*    inv_deg   = (float*)take((size_t)N * 4);
    int*      ssrc      = (int*)take((size_t)NB * BCAP * 4);        // 12.8 MB (bucket-strided)
    unsigned char* p8   = (unsigned char*)take((size_t)(N + 1) * 128);    // +sentinel row
    ushort*   q         = (ushort*)take((size_t)(N + 1) * 128 * 2);       // +sentinel row
    ushort*   hb        = (ushort*)take((size_t)N * 128 * 2);
    ushort*   Wf_l1     = (ushort*)take(128 * 128 * 2);
    ushort*   Wf_r1     = (ushort*)take(128 * 128 * 2);
    ushort*   Wf_l2     = (ushort*)take(64 * 128 * 2);
    ushort*   Wf_r2     = (ushort*)take(64 * 128 * 2);
    unsigned char* u8 = p8;   // p dead after agg_relu; u8 row N rewritten 0 by proj2
    ushort*        v  = q;    // q dead after agg_relu
    (void)ws_size; (void)n_in; (void)out_size;

    static bool attr_set = false;                   // allow 64KB dynamic LDS for k2
    if (!attr_set) {
        hipFuncSetAttribute((const void*)k2_csr_proj1,
                            hipFuncAttributeMaxDynamicSharedMemorySize, 65536);
        attr_set = true;
    }

    hipMemsetAsync(bcount, 0, (size_t)NB * 4, stream);

    // K1: scatter || weight repack (independent)
    k1_scatter_cvtw<<<NSC + 192, 256, 0, stream>>>(src, dst, bcount, bbuf, E, NSC,
                                                   Wl1, Wr1, Wl2, Wr2,
                                                   Wf_l1, Wf_r1, Wf_l2, Wf_r2);

    // K2: build_csr (padded lists, LDS entry cache) || proj1 (LDS-staged weights)
    int P1 = (N + 127) / 128;
    k2_csr_proj1<<<NB + P1, 512, 65536, stream>>>(bbuf, bcount, rsd, inv_deg,
                                                  ssrc, NB, N, x, Wf_l1, Wf_r1, b1, p8, q);

    // layer 1 aggregate (2 nodes/wave)
    agg_relu_kernel<<<(N + 7) / 8, 256, 0, stream>>>(p8, q, ssrc, rsd, inv_deg, hb, N);

    // layer 2
    proj2_kernel<<<(N + 127) / 128, 512, 0, stream>>>(hb, Wf_l2, Wf_r2, b2, u8, v, N);
    agg_lsm_kernel<<<(N + 7) / 8, 256, 0, stream>>>(u8, v, ssrc, rsd, inv_deg,
                                                    (float*)d_out, N);
}